// Round 2
// baseline (416.799 us; speedup 1.0000x reference)
//
#include <hip/hip_runtime.h>
#include <hip/hip_bf16.h>

#define Bq 2
#define Tq 2048
#define Cq 1024
#define Hq 16
#define HSq 64
#define EPSq 1e-5f

using bf16 = __hip_bfloat16;
using f32x4 = __attribute__((ext_vector_type(4))) float;
using f32x16 = __attribute__((ext_vector_type(16))) float;
using bf16x8 = __attribute__((ext_vector_type(8))) __bf16;

__device__ __forceinline__ bf16 f2bf(float f) { return __float2bfloat16(f); }
__device__ __forceinline__ unsigned short f2u(float f) {
    return __builtin_bit_cast(unsigned short, __float2bfloat16(f));
}
// async global->LDS, 16B per lane; LDS dest = wave-uniform base + lane*16
__device__ __forceinline__ void gload16(const void* g, void* l) {
    __builtin_amdgcn_global_load_lds((const __attribute__((address_space(1))) void*)g,
                                     (__attribute__((address_space(3))) void*)l, 16, 0, 0);
}

// ------------- transpose f32 src -> bf16 dst (dims multiples of 32) -------------
__global__ void k_transpose(const float* __restrict__ src, bf16* __restrict__ dst,
                            int R, int Cc, long strideSrc, long strideDst) {
    __shared__ bf16 tile[32][33];
    const long zb = blockIdx.z;
    src += zb * strideSrc;
    dst += zb * strideDst;
    int c0 = blockIdx.x * 32, r0 = blockIdx.y * 32;
    int tx = threadIdx.x & 31, ty = threadIdx.x >> 5;
    for (int i = ty; i < 32; i += 8)
        tile[i][tx] = f2bf(src[(long)(r0 + i) * Cc + (c0 + tx)]);
    __syncthreads();
    for (int i = ty; i < 32; i += 8)
        dst[(long)(c0 + i) * R + (r0 + tx)] = tile[tx][i];
}

__global__ void k_pack_bias(const float* __restrict__ a, const float* __restrict__ b,
                            const float* __restrict__ c, float* __restrict__ dst) {
    int i = blockIdx.x * 256 + threadIdx.x;  // 0..1023
    dst[i] = a[i];
    dst[1024 + i] = b[i];
    dst[2048 + i] = c[i];
}

// ---------------- LayerNorm over the SEQUENCE axis (per (b,c)), f32 in ----------
__global__ void k_ln_part(const float* __restrict__ x, float* __restrict__ ps,
                          float* __restrict__ pss) {
    int c = blockIdx.x * 256 + threadIdx.x;
    int b = blockIdx.y;
    int tc = blockIdx.z;  // 32 chunks of 64 timesteps
    const float* p = x + (long)b * Tq * Cq + (long)tc * 64 * Cq + c;
    float s = 0.f, ss = 0.f;
    for (int t = 0; t < 64; ++t) {
        float v = p[(long)t * Cq];
        s += v;
        ss += v * v;
    }
    long o = ((long)tc * Bq + b) * Cq + c;
    ps[o] = s;
    pss[o] = ss;
}

__global__ void k_ln_fin(const float* __restrict__ ps, const float* __restrict__ pss,
                         float* __restrict__ mean, float* __restrict__ rstd) {
    int i = blockIdx.x * 256 + threadIdx.x;  // b*Cq + c
    float s = 0.f, ss = 0.f;
    for (int tc = 0; tc < 32; ++tc) {
        s += ps[(long)tc * (Bq * Cq) + i];
        ss += pss[(long)tc * (Bq * Cq) + i];
    }
    float m = s / (float)Tq;
    float var = (ss - s * m) / (float)(Tq - 1);  // ddof=1 (unbiased)
    var = fmaxf(var, 0.f);
    mean[i] = m;
    rstd[i] = 1.0f / (sqrtf(var) + EPSq);  // eps OUTSIDE sqrt
}

__global__ void k_ln_apply(const float* __restrict__ x, const float* __restrict__ mean,
                           const float* __restrict__ rstd, const float* __restrict__ gamma,
                           const float* __restrict__ beta, bf16* __restrict__ out) {
    long i = (long)blockIdx.x * 256 + threadIdx.x;
    int c = (int)(i & (Cq - 1));
    long bt = i >> 10;
    int b = (int)(bt >> 11);
    float m = mean[b * Cq + c], r = rstd[b * Cq + c];
    out[i] = f2bf(gamma[c] * ((x[i] - m) * r) + beta[c]);
}

// XCD-aware bijective chunked swizzle (nwg % 8 == 0 for all our grids):
// XCD = dispatch_id % 8 gets a CONTIGUOUS chunk of the linear block space.
__device__ __forceinline__ void xcd_swizzle(int& bx, int& by) {
    const int gx = gridDim.x;
    const int nwg = gx * gridDim.y;
    const int bid = blockIdx.y * gx + blockIdx.x;
    const int swz = (bid & 7) * (nwg >> 3) + (bid >> 3);
    bx = swz % gx;
    by = swz / gx;
}

// ---------------- bf16 NT-GEMM, 128x128 tile, BK=64 (two BK=32 planes) ----------
// LDS XOR swizzle (both-sides with global_load_lds: pre-swizzled global source +
// swizzled lane-constant read offset; LDS dest stays linear):
//   store: lane fetches global slot (lane&3) ^ ((lane>>3)&3)      [f(row)=bits1-2]
//   read:  slot = quad ^ ((lane15>>1)&3)
// -> every 16-lane DS phase hits all 8 bank-groups (2 lanes each = free).
// MODE 0: +bias, scatter qkv: q SCALED x0.125 [bh][t][d], k [bh][t][d],
//         V TRANSPOSED [bh][d][t] (8B packed)
// MODE 2: relu(+bias) -> outB bf16 (FF1)
template <int MODE>
__global__ __launch_bounds__(256, 3) void k_gemm_nt(
    const bf16* __restrict__ A, int lda, const bf16* __restrict__ Bt, int ldb, int K,
    const float* __restrict__ bias, bf16* __restrict__ outB, int ldout) {
    __shared__ __bf16 sA[2][128 * 32];
    __shared__ __bf16 sB[2][128 * 32];
    int bx, by;
    xcd_swizzle(bx, by);
    const int m0 = by * 128, n0 = bx * 128;
    const int tid = threadIdx.x;
    const int lane = tid & 63, wave = tid >> 6;
    const int lane15 = lane & 15, quad = lane >> 4;
    const int wm = (wave >> 1) * 64, wn = (wave & 1) * 64;
    const int srow = wave * 16 + (lane >> 2);
    const int scol = (((lane & 3) ^ ((lane >> 3) & 3)) * 8);  // swizzled source slot
    const int sq8 = (quad ^ ((lane15 >> 1) & 3)) * 8;         // swizzled read slot
    __bf16* a00 = &sA[0][wave * 512];
    __bf16* a01 = &sA[0][2048 + wave * 512];
    __bf16* a10 = &sA[1][wave * 512];
    __bf16* a11 = &sA[1][2048 + wave * 512];
    __bf16* b00 = &sB[0][wave * 512];
    __bf16* b01 = &sB[0][2048 + wave * 512];
    __bf16* b10 = &sB[1][wave * 512];
    __bf16* b11 = &sB[1][2048 + wave * 512];
    const bf16* Ap = A + (long)(m0 + srow) * lda + scol;
    const bf16* Ap2 = Ap + 64L * lda;
    const bf16* Bp = Bt + (long)(n0 + srow) * ldb + scol;
    const bf16* Bp2 = Bp + 64L * ldb;

    f32x4 acc[4][4];
#pragma unroll
    for (int i = 0; i < 4; ++i)
#pragma unroll
        for (int j = 0; j < 4; ++j)
#pragma unroll
            for (int p = 0; p < 4; ++p) acc[i][j][p] = 0.f;

    for (int k0 = 0; k0 < K; k0 += 64) {
        __syncthreads();
        gload16(Ap + k0, a00);
        gload16(Ap2 + k0, a01);
        gload16(Ap + k0 + 32, a10);
        gload16(Ap2 + k0 + 32, a11);
        gload16(Bp + k0, b00);
        gload16(Bp2 + k0, b01);
        gload16(Bp + k0 + 32, b10);
        gload16(Bp2 + k0 + 32, b11);
        __syncthreads();
#pragma unroll
        for (int kk = 0; kk < 2; ++kk) {
            bf16x8 af[4], bfr[4];
#pragma unroll
            for (int i = 0; i < 4; ++i)
                af[i] = *(const bf16x8*)(&sA[kk][(wm + i * 16 + lane15) * 32 + sq8]);
#pragma unroll
            for (int j = 0; j < 4; ++j)
                bfr[j] = *(const bf16x8*)(&sB[kk][(wn + j * 16 + lane15) * 32 + sq8]);
#pragma unroll
            for (int i = 0; i < 4; ++i)
#pragma unroll
                for (int j = 0; j < 4; ++j)
                    acc[i][j] = __builtin_amdgcn_mfma_f32_16x16x32_bf16(af[i], bfr[j],
                                                                        acc[i][j], 0, 0, 0);
        }
    }
    // epilogue: C/D layout col=lane&15, row=quad*4+reg (m89/m91 verified)
    if (MODE == 0) {
#pragma unroll
        for (int i = 0; i < 4; ++i) {
            const int mm = m0 + wm + i * 16 + quad * 4;  // t base; p adds 0..3
            const int b = mm >> 11, t4 = mm & (Tq - 1);
#pragma unroll
            for (int j = 0; j < 4; ++j) {
                const int n = n0 + wn + j * 16 + lane15;
                const int which = n >> 10, hh = (n >> 6) & (Hq - 1), d = n & (HSq - 1);
                const long bh = (long)b * Hq + hh;
                const float bb = bias[n];
                if (which == 0) {  // q, pre-scaled by 1/8 (softmax scale folded in)
#pragma unroll
                    for (int p = 0; p < 4; ++p)
                        outB[bh * 131072 + (long)(t4 + p) * HSq + d] =
                            f2bf((acc[i][j][p] + bb) * 0.125f);
                } else if (which == 1) {  // k
#pragma unroll
                    for (int p = 0; p < 4; ++p)
                        outB[4194304L + bh * 131072 + (long)(t4 + p) * HSq + d] =
                            f2bf(acc[i][j][p] + bb);
                } else {  // V stored transposed [bh][d][t], 4 consecutive t packed
                    ushort4 pk;
                    pk.x = f2u(acc[i][j][0] + bb);
                    pk.y = f2u(acc[i][j][1] + bb);
                    pk.z = f2u(acc[i][j][2] + bb);
                    pk.w = f2u(acc[i][j][3] + bb);
                    *(ushort4*)(&outB[8388608L + bh * 131072 + (long)d * Tq + t4]) = pk;
                }
            }
        }
    } else {  // MODE 2: relu(+bias) -> bf16
#pragma unroll
        for (int i = 0; i < 4; ++i) {
#pragma unroll
            for (int p = 0; p < 4; ++p) {
                const int m = m0 + wm + i * 16 + quad * 4 + p;
#pragma unroll
                for (int j = 0; j < 4; ++j) {
                    const int n = n0 + wn + j * 16 + lane15;
                    outB[(long)m * ldout + n] = f2bf(fmaxf(acc[i][j][p] + bias[n], 0.f));
                }
            }
        }
    }
}

// ---- bf16 NT-GEMM, 128x128 tile, 2-phase prefetch pipeline (proj, FF2) --------
// Grid is N/128 x M/128 = 256 blocks = 1 block/CU: no partner block to hide the
// global_load_lds latency, so double-buffer the full BK=64 stage (64 KiB LDS) and
// issue next-tile loads BEFORE computing the current tile. One barrier per K-step
// (its implicit vmcnt(0) drains loads that have had ~900 cy of compute to land).
// out f32 = acc + bias + resid
__global__ __launch_bounds__(256, 2) void k_gemm_pf(
    const bf16* __restrict__ A, int lda, const bf16* __restrict__ Bt, int ldb, int K,
    const float* __restrict__ bias, const float* __restrict__ residF,
    float* __restrict__ outF, int ldout) {
    __shared__ __bf16 sA[2][2][128 * 32];
    __shared__ __bf16 sB[2][2][128 * 32];
    int bx, by;
    xcd_swizzle(bx, by);
    const int m0 = by * 128, n0 = bx * 128;
    const int tid = threadIdx.x;
    const int lane = tid & 63, wave = tid >> 6;
    const int lane15 = lane & 15, quad = lane >> 4;
    const int wm = (wave >> 1) * 64, wn = (wave & 1) * 64;
    const int srow = wave * 16 + (lane >> 2);
    const int scol = (((lane & 3) ^ ((lane >> 3) & 3)) * 8);
    const int sq8 = (quad ^ ((lane15 >> 1) & 3)) * 8;
    const bf16* Ap = A + (long)(m0 + srow) * lda + scol;
    const bf16* Ap2 = Ap + 64L * lda;
    const bf16* Bp = Bt + (long)(n0 + srow) * ldb + scol;
    const bf16* Bp2 = Bp + 64L * ldb;

    f32x4 acc[4][4];
#pragma unroll
    for (int i = 0; i < 4; ++i)
#pragma unroll
        for (int j = 0; j < 4; ++j)
#pragma unroll
            for (int p = 0; p < 4; ++p) acc[i][j][p] = 0.f;

#define STAGE_PF(p, ko)                                      \
    do {                                                     \
        gload16(Ap + (ko), &sA[p][0][wave * 512]);           \
        gload16(Ap2 + (ko), &sA[p][0][2048 + wave * 512]);   \
        gload16(Ap + (ko) + 32, &sA[p][1][wave * 512]);      \
        gload16(Ap2 + (ko) + 32, &sA[p][1][2048 + wave * 512]); \
        gload16(Bp + (ko), &sB[p][0][wave * 512]);           \
        gload16(Bp2 + (ko), &sB[p][0][2048 + wave * 512]);   \
        gload16(Bp + (ko) + 32, &sB[p][1][wave * 512]);      \
        gload16(Bp2 + (ko) + 32, &sB[p][1][2048 + wave * 512]); \
    } while (0)

#define COMPUTE_PF(p)                                                                   \
    do {                                                                                \
        _Pragma("unroll") for (int kk = 0; kk < 2; ++kk) {                              \
            bf16x8 af[4], bfr[4];                                                       \
            _Pragma("unroll") for (int i = 0; i < 4; ++i) af[i] =                       \
                *(const bf16x8*)(&sA[p][kk][(wm + i * 16 + lane15) * 32 + sq8]);        \
            _Pragma("unroll") for (int j = 0; j < 4; ++j) bfr[j] =                      \
                *(const bf16x8*)(&sB[p][kk][(wn + j * 16 + lane15) * 32 + sq8]);        \
            _Pragma("unroll") for (int i = 0; i < 4; ++i)                               \
                _Pragma("unroll") for (int j = 0; j < 4; ++j) acc[i][j] =               \
                    __builtin_amdgcn_mfma_f32_16x16x32_bf16(af[i], bfr[j], acc[i][j],   \
                                                            0, 0, 0);                   \
        }                                                                               \
    } while (0)

    STAGE_PF(0, 0);
    __syncthreads();  // implicit vmcnt(0): prologue stage complete
    int cur = 0;
    for (int k0 = 0; k0 < K - 64; k0 += 64) {
        STAGE_PF(cur ^ 1, k0 + 64);  // issue next tile BEFORE compute
        COMPUTE_PF(cur);
        __syncthreads();  // drains prefetch (landed under ~900cy of compute)
        cur ^= 1;
    }
    COMPUTE_PF(cur);
#undef STAGE_PF
#undef COMPUTE_PF

#pragma unroll
    for (int i = 0; i < 4; ++i) {
#pragma unroll
        for (int p = 0; p < 4; ++p) {
            const int m = m0 + wm + i * 16 + quad * 4 + p;
#pragma unroll
            for (int j = 0; j < 4; ++j) {
                const int n = n0 + wn + j * 16 + lane15;
                outF[(long)m * ldout + n] =
                    acc[i][j][p] + bias[n] + residF[(long)m * ldout + n];
            }
        }
    }
}

// ---------------- flash attention v5: S^T form, shuffle-transpose, prefetch -----
__global__ __launch_bounds__(256, 2) void k_attn(const bf16* __restrict__ qkv,
                                                 bf16* __restrict__ attn) {
    __shared__ __bf16 sK[64 * 72];
    __shared__ __bf16 sVt[64 * 72];
    const int bh = blockIdx.y;
    const int q0 = blockIdx.x * 128;
    const int tid = threadIdx.x, wave = tid >> 6, lane = tid & 63;
    const int lane31 = lane & 31, laneh = lane >> 5;
    const bf16* Qp = qkv + (long)bh * 131072;
    const bf16* Kp = qkv + 4194304L + (long)bh * 131072;
    const bf16* Vtp = qkv + 8388608L + (long)bh * 131072;
    bf16x8 qa[4];
#pragma unroll
    for (int s = 0; s < 4; ++s)
        qa[s] = *(const bf16x8*)(&Qp[(long)(q0 + wave * 32 + lane31) * HSq + s * 16 + laneh * 8]);
    f32x16 o[2];
#pragma unroll
    for (int dt = 0; dt < 2; ++dt)
#pragma unroll
        for (int r = 0; r < 16; ++r) o[dt][r] = 0.f;
    float rs = 0.f;
    const int r0 = tid >> 3, c0 = (tid & 7) * 8;
    const int r1 = r0 + 32;

    uint4 nk0 = *(const uint4*)(&Kp[(long)r0 * HSq + c0]);
    uint4 nk1 = *(const uint4*)(&Kp[(long)r1 * HSq + c0]);
    uint4 nv0 = *(const uint4*)(&Vtp[(long)r0 * Tq + c0]);
    uint4 nv1 = *(const uint4*)(&Vtp[(long)r1 * Tq + c0]);

    for (int kc = 0; kc < Tq; kc += 64) {
        __syncthreads();
        *(uint4*)(&sK[r0 * 72 + c0]) = nk0;
        *(uint4*)(&sK[r1 * 72 + c0]) = nk1;
        *(uint4*)(&sVt[r0 * 72 + c0]) = nv0;
        *(uint4*)(&sVt[r1 * 72 + c0]) = nv1;
        __syncthreads();
        if (kc + 64 < Tq) {
            nk0 = *(const uint4*)(&Kp[(long)(kc + 64 + r0) * HSq + c0]);
            nk1 = *(const uint4*)(&Kp[(long)(kc + 64 + r1) * HSq + c0]);
            nv0 = *(const uint4*)(&Vtp[(long)r0 * Tq + kc + 64 + c0]);
            nv1 = *(const uint4*)(&Vtp[(long)r1 * Tq + kc + 64 + c0]);
        }
#pragma unroll
        for (int nt = 0; nt < 2; ++nt) {
            f32x16 z;
#pragma unroll
            for (int r = 0; r < 16; ++r) z[r] = 0.f;
            __builtin_amdgcn_s_setprio(1);
#pragma unroll
            for (int s = 0; s < 4; ++s) {
                bf16x8 kb =
                    *(const bf16x8*)(&sK[(nt * 32 + lane31) * 72 + s * 16 + laneh * 8]);
                z = __builtin_amdgcn_mfma_f32_32x32x16_bf16(kb, qa[s], z, 0, 0, 0);
            }
            __builtin_amdgcn_s_setprio(0);
            float e[16];
#pragma unroll
            for (int r = 0; r < 16; ++r) {
                e[r] = __expf(z[r]);
                rs += e[r];
            }
            unsigned int pk[8];
#pragma unroll
            for (int g = 0; g < 4; ++g)
#pragma unroll
                for (int h = 0; h < 2; ++h)
                    pk[g * 2 + h] = (unsigned int)f2u(e[g * 4 + 2 * h]) |
                                    ((unsigned int)f2u(e[g * 4 + 2 * h + 1]) << 16);
            unsigned int sa0 = laneh ? pk[0] : pk[2], sa1 = laneh ? pk[1] : pk[3];
            unsigned int ra0 = __shfl_xor((int)sa0, 32), ra1 = __shfl_xor((int)sa1, 32);
            unsigned int sb0 = laneh ? pk[4] : pk[6], sb1 = laneh ? pk[5] : pk[7];
            unsigned int rb0 = __shfl_xor((int)sb0, 32), rb1 = __shfl_xor((int)sb1, 32);
            uint4 f0, f1;
            if (laneh == 0) {
                f0 = {pk[0], pk[1], ra0, ra1};
                f1 = {pk[4], pk[5], rb0, rb1};
            } else {
                f0 = {ra0, ra1, pk[2], pk[3]};
                f1 = {rb0, rb1, pk[6], pk[7]};
            }
            bf16x8 pa0 = __builtin_bit_cast(bf16x8, f0);
            bf16x8 pa1 = __builtin_bit_cast(bf16x8, f1);
            __builtin_amdgcn_s_setprio(1);
#pragma unroll
            for (int dt = 0; dt < 2; ++dt) {
                bf16x8 vb0 =
                    *(const bf16x8*)(&sVt[(dt * 32 + lane31) * 72 + nt * 32 + laneh * 8]);
                bf16x8 vb1 = *(const bf16x8*)(&sVt[(dt * 32 + lane31) * 72 + nt * 32 + 16 +
                                                   laneh * 8]);
                o[dt] = __builtin_amdgcn_mfma_f32_32x32x16_bf16(pa0, vb0, o[dt], 0, 0, 0);
                o[dt] = __builtin_amdgcn_mfma_f32_32x32x16_bf16(pa1, vb1, o[dt], 0, 0, 0);
            }
            __builtin_amdgcn_s_setprio(0);
        }
    }
    float ltot = rs + __shfl_xor(rs, 32);
    float linv = 1.0f / ltot;
    const int b = bh >> 4, hh = bh & 15;
#pragma unroll
    for (int r = 0; r < 16; ++r) {
        const int tl = (r & 3) + 8 * (r >> 2) + 4 * laneh;
        float inv = __shfl(linv, tl);
        const int t = q0 + wave * 32 + tl;
        const long base = ((long)b * Tq + t) * Cq + hh * HSq;
#pragma unroll
        for (int dt = 0; dt < 2; ++dt)
            attn[base + dt * 32 + lane31] = f2bf(o[dt][r] * inv);
    }
}

extern "C" void kernel_launch(void* const* d_in, const int* in_sizes, int n_in,
                              void* d_out, int out_size, void* d_ws, size_t ws_size,
                              hipStream_t stream) {
    const float* x = (const float*)d_in[0];
    const float* Wq = (const float*)d_in[1];
    const float* bqv = (const float*)d_in[2];
    const float* Wk = (const float*)d_in[3];
    const float* bkv = (const float*)d_in[4];
    const float* Wv = (const float*)d_in[5];
    const float* bvv = (const float*)d_in[6];
    const float* Wo = (const float*)d_in[7];
    const float* bo = (const float*)d_in[8];
    const float* W1 = (const float*)d_in[9];
    const float* b1 = (const float*)d_in[10];
    const float* W2 = (const float*)d_in[11];
    const float* b2 = (const float*)d_in[12];
    const float* g1 = (const float*)d_in[13];
    const float* be1 = (const float*)d_in[14];
    const float* g2 = (const float*)d_in[15];
    const float* be2 = (const float*)d_in[16];

    // ---- workspace: ~56.7 MiB total (safe under 64 MiB) ----
    char* ws = (char*)d_ws;
    size_t off = 0;
    auto alloc = [&](size_t bytes) {
        void* p = ws + off;
        off += (bytes + 255) & ~(size_t)255;
        return p;
    };
    bf16* regA = (bf16*)alloc(32L * 1024 * 1024);  // qkv (24 MiB) then a1 [4096][4096] (32 MiB)
    float* x2 = (float*)alloc(4096L * 1024 * 4);   // 16 MiB f32 residual
    bf16* buf1 = (bf16*)alloc(4096L * 1024 * 2);   // 8 MiB: WqkvT -> WoT -> W1T -> W2T
    float* bqkv = (float*)alloc(3072L * 4);
    float* ps = (float*)alloc(32L * Bq * Cq * 4);
    float* pss = (float*)alloc(32L * Bq * Cq * 4);
    float* mean1 = (float*)alloc(Bq * Cq * 4);
    float* rstd1 = (float*)alloc(Bq * Cq * 4);
    float* mean2 = (float*)alloc(Bq * Cq * 4);
    float* rstd2 = (float*)alloc(Bq * Cq * 4);
    bf16* dres = (bf16*)d_out;  // d_out first 8 MiB as bf16 scratch: h -> attn -> h2
    float* outF = (float*)d_out;

    // LN1 -> h (bf16, in d_out)
    k_ln_part<<<dim3(4, Bq, 32), 256, 0, stream>>>(x, ps, pss);
    k_ln_fin<<<dim3(8), 256, 0, stream>>>(ps, pss, mean1, rstd1);
    k_ln_apply<<<dim3(16384), 256, 0, stream>>>(x, mean1, rstd1, g1, be1, dres);

    // Wq/Wk/Wv [16][1024][64] f32 -> per-head transpose -> buf1 [3072][1024] bf16
    k_transpose<<<dim3(2, 32, 16), 256, 0, stream>>>(Wq, buf1, 1024, 64, 65536, 65536);
    k_transpose<<<dim3(2, 32, 16), 256, 0, stream>>>(Wk, buf1 + 1048576, 1024, 64, 65536, 65536);
    k_transpose<<<dim3(2, 32, 16), 256, 0, stream>>>(Wv, buf1 + 2097152, 1024, 64, 65536, 65536);
    k_pack_bias<<<dim3(4), 256, 0, stream>>>(bqv, bkv, bvv, bqkv);
    // QKV projection -> q(scaled),k,vt in regA
    k_gemm_nt<0><<<dim3(24, 32), 256, 0, stream>>>(dres, 1024, buf1, 1024, 1024, bqkv, regA, 0);
    // attention -> attn (bf16, overwrites h in d_out)
    k_attn<<<dim3(16, 32), 256, 0, stream>>>(regA, dres);
    // Wo^T -> buf1; x2 = attn@Wo + bo + x   (128x128 prefetch tiles, 256 blocks)
    k_transpose<<<dim3(32, 32, 1), 256, 0, stream>>>(Wo, buf1, 1024, 1024, 0, 0);
    k_gemm_pf<<<dim3(8, 32), 256, 0, stream>>>(dres, 1024, buf1, 1024, 1024, bo, x, x2, 1024);
    // LN2 -> h2 (bf16, overwrites attn in d_out)
    k_ln_part<<<dim3(4, Bq, 32), 256, 0, stream>>>(x2, ps, pss);
    k_ln_fin<<<dim3(8), 256, 0, stream>>>(ps, pss, mean2, rstd2);
    k_ln_apply<<<dim3(16384), 256, 0, stream>>>(x2, mean2, rstd2, g2, be2, dres);

    // ---- FF ----
    k_transpose<<<dim3(128, 32, 1), 256, 0, stream>>>(W1, buf1, 1024, 4096, 0, 0);  // W1T [4096][1024]
    // a1 = relu(h2 @ W1T + b1) -> regA [4096][4096] bf16 (qkv dead)
    k_gemm_nt<2><<<dim3(32, 32), 256, 0, stream>>>(dres, 1024, buf1, 1024, 1024, b1, regA, 4096);
    k_transpose<<<dim3(32, 128, 1), 256, 0, stream>>>(W2, buf1, 4096, 1024, 0, 0);  // W2T [1024][4096]
    // d_out(f32) = a1 @ W2T + b2 + x2   (128x128 prefetch tiles, 256 blocks)
    k_gemm_pf<<<dim3(8, 32), 256, 0, stream>>>(regA, 4096, buf1, 4096, 4096, b2, x2, outF,
                                               1024);
}

// Round 3
// 392.607 us; speedup vs baseline: 1.0616x; 1.0616x over previous
//
#include <hip/hip_runtime.h>
#include <hip/hip_bf16.h>

#define Bq 2
#define Tq 2048
#define Cq 1024
#define Hq 16
#define HSq 64
#define EPSq 1e-5f

using bf16 = __hip_bfloat16;
using f32x4 = __attribute__((ext_vector_type(4))) float;
using f32x16 = __attribute__((ext_vector_type(16))) float;
using bf16x8 = __attribute__((ext_vector_type(8))) __bf16;

__device__ __forceinline__ bf16 f2bf(float f) { return __float2bfloat16(f); }
__device__ __forceinline__ unsigned short f2u(float f) {
    return __builtin_bit_cast(unsigned short, __float2bfloat16(f));
}
// async global->LDS, 16B per lane; LDS dest = wave-uniform base + lane*16
__device__ __forceinline__ void gload16(const void* g, void* l) {
    __builtin_amdgcn_global_load_lds((const __attribute__((address_space(1))) void*)g,
                                     (__attribute__((address_space(3))) void*)l, 16, 0, 0);
}

// ------------- transpose f32 src -> bf16 dst (dims multiples of 32) -------------
__global__ void k_transpose(const float* __restrict__ src, bf16* __restrict__ dst,
                            int R, int Cc, long strideSrc, long strideDst) {
    __shared__ bf16 tile[32][33];
    const long zb = blockIdx.z;
    src += zb * strideSrc;
    dst += zb * strideDst;
    int c0 = blockIdx.x * 32, r0 = blockIdx.y * 32;
    int tx = threadIdx.x & 31, ty = threadIdx.x >> 5;
    for (int i = ty; i < 32; i += 8)
        tile[i][tx] = f2bf(src[(long)(r0 + i) * Cc + (c0 + tx)]);
    __syncthreads();
    for (int i = ty; i < 32; i += 8)
        dst[(long)(c0 + i) * R + (r0 + tx)] = tile[tx][i];
}

__global__ void k_pack_bias(const float* __restrict__ a, const float* __restrict__ b,
                            const float* __restrict__ c, float* __restrict__ dst) {
    int i = blockIdx.x * 256 + threadIdx.x;  // 0..1023
    dst[i] = a[i];
    dst[1024 + i] = b[i];
    dst[2048 + i] = c[i];
}

// ---------------- LayerNorm over the SEQUENCE axis (per (b,c)), f32 in ----------
__global__ void k_ln_part(const float* __restrict__ x, float* __restrict__ ps,
                          float* __restrict__ pss) {
    int c = blockIdx.x * 256 + threadIdx.x;
    int b = blockIdx.y;
    int tc = blockIdx.z;  // 32 chunks of 64 timesteps
    const float* p = x + (long)b * Tq * Cq + (long)tc * 64 * Cq + c;
    float s = 0.f, ss = 0.f;
    for (int t = 0; t < 64; ++t) {
        float v = p[(long)t * Cq];
        s += v;
        ss += v * v;
    }
    long o = ((long)tc * Bq + b) * Cq + c;
    ps[o] = s;
    pss[o] = ss;
}

__global__ void k_ln_fin(const float* __restrict__ ps, const float* __restrict__ pss,
                         float* __restrict__ mean, float* __restrict__ rstd) {
    int i = blockIdx.x * 256 + threadIdx.x;  // b*Cq + c
    float s = 0.f, ss = 0.f;
    for (int tc = 0; tc < 32; ++tc) {
        s += ps[(long)tc * (Bq * Cq) + i];
        ss += pss[(long)tc * (Bq * Cq) + i];
    }
    float m = s / (float)Tq;
    float var = (ss - s * m) / (float)(Tq - 1);  // ddof=1 (unbiased)
    var = fmaxf(var, 0.f);
    mean[i] = m;
    rstd[i] = 1.0f / (sqrtf(var) + EPSq);  // eps OUTSIDE sqrt
}

__global__ void k_ln_apply(const float* __restrict__ x, const float* __restrict__ mean,
                           const float* __restrict__ rstd, const float* __restrict__ gamma,
                           const float* __restrict__ beta, bf16* __restrict__ out) {
    long i = (long)blockIdx.x * 256 + threadIdx.x;
    int c = (int)(i & (Cq - 1));
    long bt = i >> 10;
    int b = (int)(bt >> 11);
    float m = mean[b * Cq + c], r = rstd[b * Cq + c];
    out[i] = f2bf(gamma[c] * ((x[i] - m) * r) + beta[c]);
}

// XCD-aware bijective chunked swizzle (nwg % 8 == 0 for all our grids):
// XCD c = bid%8 gets a CONTIGUOUS chunk of row-major tile space -> within an
// XCD, consecutive by-tiles share A panels (L2-resident) and all bx share B.
__device__ __forceinline__ void xcd_swizzle(int& bx, int& by) {
    const int gx = gridDim.x;
    const int nwg = gx * gridDim.y;
    const int bid = blockIdx.y * gx + blockIdx.x;
    const int swz = (bid & 7) * (nwg >> 3) + (bid >> 3);
    bx = swz % gx;
    by = swz / gx;
}

// ---------------- bf16 NT-GEMM, 128x128 tile, BK=64 (two BK=32 planes) ----------
// LDS XOR swizzle (both-sides with global_load_lds: pre-swizzled global source +
// swizzled lane-constant read offset; LDS dest stays linear):
//   store: lane fetches global slot (lane&3) ^ ((lane>>3)&3)      [f(row)=bits1-2]
//   read:  slot = quad ^ ((lane15>>1)&3)
// -> every 16-lane DS phase hits all 8 bank-groups (2 lanes each = free).
// Verified: conflicts 6.3M -> 0, absmax unchanged (round 2).
// MODE 0: +bias, scatter qkv: q SCALED x0.125 [bh][t][d], k [bh][t][d],
//         V TRANSPOSED [bh][d][t] (8B packed)
// MODE 2: relu(+bias) -> outB bf16 (FF1)
template <int MODE>
__global__ __launch_bounds__(256, 3) void k_gemm_nt(
    const bf16* __restrict__ A, int lda, const bf16* __restrict__ Bt, int ldb, int K,
    const float* __restrict__ bias, bf16* __restrict__ outB, int ldout) {
    __shared__ __bf16 sA[2][128 * 32];
    __shared__ __bf16 sB[2][128 * 32];
    int bx, by;
    xcd_swizzle(bx, by);
    const int m0 = by * 128, n0 = bx * 128;
    const int tid = threadIdx.x;
    const int lane = tid & 63, wave = tid >> 6;
    const int lane15 = lane & 15, quad = lane >> 4;
    const int wm = (wave >> 1) * 64, wn = (wave & 1) * 64;
    const int srow = wave * 16 + (lane >> 2);
    const int scol = (((lane & 3) ^ ((lane >> 3) & 3)) * 8);  // swizzled source slot
    const int sq8 = (quad ^ ((lane15 >> 1) & 3)) * 8;         // swizzled read slot
    __bf16* a00 = &sA[0][wave * 512];
    __bf16* a01 = &sA[0][2048 + wave * 512];
    __bf16* a10 = &sA[1][wave * 512];
    __bf16* a11 = &sA[1][2048 + wave * 512];
    __bf16* b00 = &sB[0][wave * 512];
    __bf16* b01 = &sB[0][2048 + wave * 512];
    __bf16* b10 = &sB[1][wave * 512];
    __bf16* b11 = &sB[1][2048 + wave * 512];
    const bf16* Ap = A + (long)(m0 + srow) * lda + scol;
    const bf16* Ap2 = Ap + 64L * lda;
    const bf16* Bp = Bt + (long)(n0 + srow) * ldb + scol;
    const bf16* Bp2 = Bp + 64L * ldb;

    f32x4 acc[4][4];
#pragma unroll
    for (int i = 0; i < 4; ++i)
#pragma unroll
        for (int j = 0; j < 4; ++j)
#pragma unroll
            for (int p = 0; p < 4; ++p) acc[i][j][p] = 0.f;

    for (int k0 = 0; k0 < K; k0 += 64) {
        __syncthreads();
        gload16(Ap + k0, a00);
        gload16(Ap2 + k0, a01);
        gload16(Ap + k0 + 32, a10);
        gload16(Ap2 + k0 + 32, a11);
        gload16(Bp + k0, b00);
        gload16(Bp2 + k0, b01);
        gload16(Bp + k0 + 32, b10);
        gload16(Bp2 + k0 + 32, b11);
        __syncthreads();
#pragma unroll
        for (int kk = 0; kk < 2; ++kk) {
            bf16x8 af[4], bfr[4];
#pragma unroll
            for (int i = 0; i < 4; ++i)
                af[i] = *(const bf16x8*)(&sA[kk][(wm + i * 16 + lane15) * 32 + sq8]);
#pragma unroll
            for (int j = 0; j < 4; ++j)
                bfr[j] = *(const bf16x8*)(&sB[kk][(wn + j * 16 + lane15) * 32 + sq8]);
#pragma unroll
            for (int i = 0; i < 4; ++i)
#pragma unroll
                for (int j = 0; j < 4; ++j)
                    acc[i][j] = __builtin_amdgcn_mfma_f32_16x16x32_bf16(af[i], bfr[j],
                                                                        acc[i][j], 0, 0, 0);
        }
    }
    // epilogue: C/D layout col=lane&15, row=quad*4+reg (m89/m91 verified)
    if (MODE == 0) {
#pragma unroll
        for (int i = 0; i < 4; ++i) {
            const int mm = m0 + wm + i * 16 + quad * 4;  // t base; p adds 0..3
            const int b = mm >> 11, t4 = mm & (Tq - 1);
#pragma unroll
            for (int j = 0; j < 4; ++j) {
                const int n = n0 + wn + j * 16 + lane15;
                const int which = n >> 10, hh = (n >> 6) & (Hq - 1), d = n & (HSq - 1);
                const long bh = (long)b * Hq + hh;
                const float bb = bias[n];
                if (which == 0) {  // q, pre-scaled by 1/8 (softmax scale folded in)
#pragma unroll
                    for (int p = 0; p < 4; ++p)
                        outB[bh * 131072 + (long)(t4 + p) * HSq + d] =
                            f2bf((acc[i][j][p] + bb) * 0.125f);
                } else if (which == 1) {  // k
#pragma unroll
                    for (int p = 0; p < 4; ++p)
                        outB[4194304L + bh * 131072 + (long)(t4 + p) * HSq + d] =
                            f2bf(acc[i][j][p] + bb);
                } else {  // V stored transposed [bh][d][t], 4 consecutive t packed
                    ushort4 pk;
                    pk.x = f2u(acc[i][j][0] + bb);
                    pk.y = f2u(acc[i][j][1] + bb);
                    pk.z = f2u(acc[i][j][2] + bb);
                    pk.w = f2u(acc[i][j][3] + bb);
                    *(ushort4*)(&outB[8388608L + bh * 131072 + (long)d * Tq + t4]) = pk;
                }
            }
        }
    } else {  // MODE 2: relu(+bias) -> bf16
#pragma unroll
        for (int i = 0; i < 4; ++i) {
#pragma unroll
            for (int p = 0; p < 4; ++p) {
                const int m = m0 + wm + i * 16 + quad * 4 + p;
#pragma unroll
                for (int j = 0; j < 4; ++j) {
                    const int n = n0 + wn + j * 16 + lane15;
                    outB[(long)m * ldout + n] = f2bf(fmaxf(acc[i][j][p] + bias[n], 0.f));
                }
            }
        }
    }
}

// ---------------- bf16 NT-GEMM, 128x64 tile, BK=64 (proj, FF2) ------------------
// 512 blocks = 2 blocks/CU: cross-block overlap hides the stage+drain chain
// (the 128x128 1-block/CU prefetch variant measured 89us vs this structure's 63;
// bulk-synchronous vmcnt(0) drains were fully exposed). Conflict-free read
// swizzle + XCD chunking grafted on (both verified in round 2).
// MODE 1/3: outF = acc + bias + residF (f32)
template <int MODE>
__global__ __launch_bounds__(256, 4) void k_gemm_n64(
    const bf16* __restrict__ A, int lda, const bf16* __restrict__ Bt, int ldb, int K,
    const float* __restrict__ bias, const float* __restrict__ residF,
    float* __restrict__ outF, int ldout) {
    __shared__ __bf16 sA[2][128 * 32];
    __shared__ __bf16 sB[2][64 * 32];
    int bx, by;
    xcd_swizzle(bx, by);
    const int m0 = by * 128, n0 = bx * 64;
    const int tid = threadIdx.x;
    const int lane = tid & 63, wave = tid >> 6;
    const int lane15 = lane & 15, quad = lane >> 4;
    const int wm = wave * 32;  // each wave: 32 rows x 64 cols
    const int srow = wave * 16 + (lane >> 2);
    const int scol = (((lane & 3) ^ ((lane >> 3) & 3)) * 8);  // swizzled source slot
    const int sq8 = (quad ^ ((lane15 >> 1) & 3)) * 8;         // swizzled read slot
    __bf16* a00 = &sA[0][wave * 512];
    __bf16* a01 = &sA[0][2048 + wave * 512];
    __bf16* a10 = &sA[1][wave * 512];
    __bf16* a11 = &sA[1][2048 + wave * 512];
    __bf16* b00 = &sB[0][wave * 512];
    __bf16* b10 = &sB[1][wave * 512];
    const bf16* Ap = A + (long)(m0 + srow) * lda + scol;
    const bf16* Ap2 = Ap + 64L * lda;
    const bf16* Bp = Bt + (long)(n0 + srow) * ldb + scol;

    f32x4 acc[2][4];
#pragma unroll
    for (int i = 0; i < 2; ++i)
#pragma unroll
        for (int j = 0; j < 4; ++j)
#pragma unroll
            for (int p = 0; p < 4; ++p) acc[i][j][p] = 0.f;

    for (int k0 = 0; k0 < K; k0 += 64) {
        __syncthreads();
        gload16(Ap + k0, a00);
        gload16(Ap2 + k0, a01);
        gload16(Ap + k0 + 32, a10);
        gload16(Ap2 + k0 + 32, a11);
        gload16(Bp + k0, b00);
        gload16(Bp + k0 + 32, b10);
        __syncthreads();
#pragma unroll
        for (int kk = 0; kk < 2; ++kk) {
            bf16x8 af[2], bfr[4];
#pragma unroll
            for (int i = 0; i < 2; ++i)
                af[i] = *(const bf16x8*)(&sA[kk][(wm + i * 16 + lane15) * 32 + sq8]);
#pragma unroll
            for (int j = 0; j < 4; ++j)
                bfr[j] = *(const bf16x8*)(&sB[kk][(j * 16 + lane15) * 32 + sq8]);
#pragma unroll
            for (int i = 0; i < 2; ++i)
#pragma unroll
                for (int j = 0; j < 4; ++j)
                    acc[i][j] = __builtin_amdgcn_mfma_f32_16x16x32_bf16(af[i], bfr[j],
                                                                        acc[i][j], 0, 0, 0);
        }
    }
#pragma unroll
    for (int i = 0; i < 2; ++i) {
#pragma unroll
        for (int p = 0; p < 4; ++p) {
            const int m = m0 + wm + i * 16 + quad * 4 + p;
#pragma unroll
            for (int j = 0; j < 4; ++j) {
                const int n = n0 + j * 16 + lane15;
                outF[(long)m * ldout + n] =
                    acc[i][j][p] + bias[n] + residF[(long)m * ldout + n];
            }
        }
    }
}

// ---------------- flash attention v5: S^T form, shuffle-transpose, prefetch -----
__global__ __launch_bounds__(256, 2) void k_attn(const bf16* __restrict__ qkv,
                                                 bf16* __restrict__ attn) {
    __shared__ __bf16 sK[64 * 72];
    __shared__ __bf16 sVt[64 * 72];
    const int bh = blockIdx.y;
    const int q0 = blockIdx.x * 128;
    const int tid = threadIdx.x, wave = tid >> 6, lane = tid & 63;
    const int lane31 = lane & 31, laneh = lane >> 5;
    const bf16* Qp = qkv + (long)bh * 131072;
    const bf16* Kp = qkv + 4194304L + (long)bh * 131072;
    const bf16* Vtp = qkv + 8388608L + (long)bh * 131072;
    bf16x8 qa[4];
#pragma unroll
    for (int s = 0; s < 4; ++s)
        qa[s] = *(const bf16x8*)(&Qp[(long)(q0 + wave * 32 + lane31) * HSq + s * 16 + laneh * 8]);
    f32x16 o[2];
#pragma unroll
    for (int dt = 0; dt < 2; ++dt)
#pragma unroll
        for (int r = 0; r < 16; ++r) o[dt][r] = 0.f;
    float rs = 0.f;
    const int r0 = tid >> 3, c0 = (tid & 7) * 8;
    const int r1 = r0 + 32;

    uint4 nk0 = *(const uint4*)(&Kp[(long)r0 * HSq + c0]);
    uint4 nk1 = *(const uint4*)(&Kp[(long)r1 * HSq + c0]);
    uint4 nv0 = *(const uint4*)(&Vtp[(long)r0 * Tq + c0]);
    uint4 nv1 = *(const uint4*)(&Vtp[(long)r1 * Tq + c0]);

    for (int kc = 0; kc < Tq; kc += 64) {
        __syncthreads();
        *(uint4*)(&sK[r0 * 72 + c0]) = nk0;
        *(uint4*)(&sK[r1 * 72 + c0]) = nk1;
        *(uint4*)(&sVt[r0 * 72 + c0]) = nv0;
        *(uint4*)(&sVt[r1 * 72 + c0]) = nv1;
        __syncthreads();
        if (kc + 64 < Tq) {
            nk0 = *(const uint4*)(&Kp[(long)(kc + 64 + r0) * HSq + c0]);
            nk1 = *(const uint4*)(&Kp[(long)(kc + 64 + r1) * HSq + c0]);
            nv0 = *(const uint4*)(&Vtp[(long)r0 * Tq + kc + 64 + c0]);
            nv1 = *(const uint4*)(&Vtp[(long)r1 * Tq + kc + 64 + c0]);
        }
#pragma unroll
        for (int nt = 0; nt < 2; ++nt) {
            f32x16 z;
#pragma unroll
            for (int r = 0; r < 16; ++r) z[r] = 0.f;
            __builtin_amdgcn_s_setprio(1);
#pragma unroll
            for (int s = 0; s < 4; ++s) {
                bf16x8 kb =
                    *(const bf16x8*)(&sK[(nt * 32 + lane31) * 72 + s * 16 + laneh * 8]);
                z = __builtin_amdgcn_mfma_f32_32x32x16_bf16(kb, qa[s], z, 0, 0, 0);
            }
            __builtin_amdgcn_s_setprio(0);
            float e[16];
#pragma unroll
            for (int r = 0; r < 16; ++r) {
                e[r] = __expf(z[r]);
                rs += e[r];
            }
            unsigned int pk[8];
#pragma unroll
            for (int g = 0; g < 4; ++g)
#pragma unroll
                for (int h = 0; h < 2; ++h)
                    pk[g * 2 + h] = (unsigned int)f2u(e[g * 4 + 2 * h]) |
                                    ((unsigned int)f2u(e[g * 4 + 2 * h + 1]) << 16);
            unsigned int sa0 = laneh ? pk[0] : pk[2], sa1 = laneh ? pk[1] : pk[3];
            unsigned int ra0 = __shfl_xor((int)sa0, 32), ra1 = __shfl_xor((int)sa1, 32);
            unsigned int sb0 = laneh ? pk[4] : pk[6], sb1 = laneh ? pk[5] : pk[7];
            unsigned int rb0 = __shfl_xor((int)sb0, 32), rb1 = __shfl_xor((int)sb1, 32);
            uint4 f0, f1;
            if (laneh == 0) {
                f0 = {pk[0], pk[1], ra0, ra1};
                f1 = {pk[4], pk[5], rb0, rb1};
            } else {
                f0 = {ra0, ra1, pk[2], pk[3]};
                f1 = {rb0, rb1, pk[6], pk[7]};
            }
            bf16x8 pa0 = __builtin_bit_cast(bf16x8, f0);
            bf16x8 pa1 = __builtin_bit_cast(bf16x8, f1);
            __builtin_amdgcn_s_setprio(1);
#pragma unroll
            for (int dt = 0; dt < 2; ++dt) {
                bf16x8 vb0 =
                    *(const bf16x8*)(&sVt[(dt * 32 + lane31) * 72 + nt * 32 + laneh * 8]);
                bf16x8 vb1 = *(const bf16x8*)(&sVt[(dt * 32 + lane31) * 72 + nt * 32 + 16 +
                                                   laneh * 8]);
                o[dt] = __builtin_amdgcn_mfma_f32_32x32x16_bf16(pa0, vb0, o[dt], 0, 0, 0);
                o[dt] = __builtin_amdgcn_mfma_f32_32x32x16_bf16(pa1, vb1, o[dt], 0, 0, 0);
            }
            __builtin_amdgcn_s_setprio(0);
        }
    }
    float ltot = rs + __shfl_xor(rs, 32);
    float linv = 1.0f / ltot;
    const int b = bh >> 4, hh = bh & 15;
#pragma unroll
    for (int r = 0; r < 16; ++r) {
        const int tl = (r & 3) + 8 * (r >> 2) + 4 * laneh;
        float inv = __shfl(linv, tl);
        const int t = q0 + wave * 32 + tl;
        const long base = ((long)b * Tq + t) * Cq + hh * HSq;
#pragma unroll
        for (int dt = 0; dt < 2; ++dt)
            attn[base + dt * 32 + lane31] = f2bf(o[dt][r] * inv);
    }
}

extern "C" void kernel_launch(void* const* d_in, const int* in_sizes, int n_in,
                              void* d_out, int out_size, void* d_ws, size_t ws_size,
                              hipStream_t stream) {
    const float* x = (const float*)d_in[0];
    const float* Wq = (const float*)d_in[1];
    const float* bqv = (const float*)d_in[2];
    const float* Wk = (const float*)d_in[3];
    const float* bkv = (const float*)d_in[4];
    const float* Wv = (const float*)d_in[5];
    const float* bvv = (const float*)d_in[6];
    const float* Wo = (const float*)d_in[7];
    const float* bo = (const float*)d_in[8];
    const float* W1 = (const float*)d_in[9];
    const float* b1 = (const float*)d_in[10];
    const float* W2 = (const float*)d_in[11];
    const float* b2 = (const float*)d_in[12];
    const float* g1 = (const float*)d_in[13];
    const float* be1 = (const float*)d_in[14];
    const float* g2 = (const float*)d_in[15];
    const float* be2 = (const float*)d_in[16];

    // ---- workspace: ~56.7 MiB total (safe under 64 MiB) ----
    char* ws = (char*)d_ws;
    size_t off = 0;
    auto alloc = [&](size_t bytes) {
        void* p = ws + off;
        off += (bytes + 255) & ~(size_t)255;
        return p;
    };
    bf16* regA = (bf16*)alloc(32L * 1024 * 1024);  // qkv (24 MiB) then a1 [4096][4096] (32 MiB)
    float* x2 = (float*)alloc(4096L * 1024 * 4);   // 16 MiB f32 residual
    bf16* buf1 = (bf16*)alloc(4096L * 1024 * 2);   // 8 MiB: WqkvT -> WoT -> W1T -> W2T
    float* bqkv = (float*)alloc(3072L * 4);
    float* ps = (float*)alloc(32L * Bq * Cq * 4);
    float* pss = (float*)alloc(32L * Bq * Cq * 4);
    float* mean1 = (float*)alloc(Bq * Cq * 4);
    float* rstd1 = (float*)alloc(Bq * Cq * 4);
    float* mean2 = (float*)alloc(Bq * Cq * 4);
    float* rstd2 = (float*)alloc(Bq * Cq * 4);
    bf16* dres = (bf16*)d_out;  // d_out first 8 MiB as bf16 scratch: h -> attn -> h2
    float* outF = (float*)d_out;

    // LN1 -> h (bf16, in d_out)
    k_ln_part<<<dim3(4, Bq, 32), 256, 0, stream>>>(x, ps, pss);
    k_ln_fin<<<dim3(8), 256, 0, stream>>>(ps, pss, mean1, rstd1);
    k_ln_apply<<<dim3(16384), 256, 0, stream>>>(x, mean1, rstd1, g1, be1, dres);

    // Wq/Wk/Wv [16][1024][64] f32 -> per-head transpose -> buf1 [3072][1024] bf16
    k_transpose<<<dim3(2, 32, 16), 256, 0, stream>>>(Wq, buf1, 1024, 64, 65536, 65536);
    k_transpose<<<dim3(2, 32, 16), 256, 0, stream>>>(Wk, buf1 + 1048576, 1024, 64, 65536, 65536);
    k_transpose<<<dim3(2, 32, 16), 256, 0, stream>>>(Wv, buf1 + 2097152, 1024, 64, 65536, 65536);
    k_pack_bias<<<dim3(4), 256, 0, stream>>>(bqv, bkv, bvv, bqkv);
    // QKV projection -> q(scaled),k,vt in regA
    k_gemm_nt<0><<<dim3(24, 32), 256, 0, stream>>>(dres, 1024, buf1, 1024, 1024, bqkv, regA, 0);
    // attention -> attn (bf16, overwrites h in d_out)
    k_attn<<<dim3(16, 32), 256, 0, stream>>>(regA, dres);
    // Wo^T -> buf1; x2 = attn@Wo + bo + x   (128x64 tiles, 512 blocks, 2/CU)
    k_transpose<<<dim3(32, 32, 1), 256, 0, stream>>>(Wo, buf1, 1024, 1024, 0, 0);
    k_gemm_n64<1><<<dim3(16, 32), 256, 0, stream>>>(dres, 1024, buf1, 1024, 1024, bo, x, x2,
                                                    1024);
    // LN2 -> h2 (bf16, overwrites attn in d_out)
    k_ln_part<<<dim3(4, Bq, 32), 256, 0, stream>>>(x2, ps, pss);
    k_ln_fin<<<dim3(8), 256, 0, stream>>>(ps, pss, mean2, rstd2);
    k_ln_apply<<<dim3(16384), 256, 0, stream>>>(x2, mean2, rstd2, g2, be2, dres);

    // ---- FF ----
    k_transpose<<<dim3(128, 32, 1), 256, 0, stream>>>(W1, buf1, 1024, 4096, 0, 0);  // W1T [4096][1024]
    // a1 = relu(h2 @ W1T + b1) -> regA [4096][4096] bf16 (qkv dead)
    k_gemm_nt<2><<<dim3(32, 32), 256, 0, stream>>>(dres, 1024, buf1, 1024, 1024, b1, regA, 4096);
    k_transpose<<<dim3(32, 128, 1), 256, 0, stream>>>(W2, buf1, 4096, 1024, 0, 0);  // W2T [1024][4096]
    // d_out(f32) = a1 @ W2T + b2 + x2   (128x64 tiles, 512 blocks, 2/CU)
    k_gemm_n64<3><<<dim3(16, 32), 256, 0, stream>>>(regA, 4096, buf1, 4096, 4096, b2, x2, outF,
                                                    1024);
}

// Round 4
// 389.041 us; speedup vs baseline: 1.0713x; 1.0092x over previous
//
#include <hip/hip_runtime.h>
#include <hip/hip_bf16.h>

#define Bq 2
#define Tq 2048
#define Cq 1024
#define Hq 16
#define HSq 64
#define EPSq 1e-5f

using bf16 = __hip_bfloat16;
using f32x4 = __attribute__((ext_vector_type(4))) float;
using f32x16 = __attribute__((ext_vector_type(16))) float;
using bf16x8 = __attribute__((ext_vector_type(8))) __bf16;

__device__ __forceinline__ bf16 f2bf(float f) { return __float2bfloat16(f); }
__device__ __forceinline__ unsigned short f2u(float f) {
    return __builtin_bit_cast(unsigned short, __float2bfloat16(f));
}
// async global->LDS, 16B per lane; LDS dest = wave-uniform base + lane*16
__device__ __forceinline__ void gload16(const void* g, void* l) {
    __builtin_amdgcn_global_load_lds((const __attribute__((address_space(1))) void*)g,
                                     (__attribute__((address_space(3))) void*)l, 16, 0, 0);
}

// ------------- transpose f32 src -> bf16 dst (dims multiples of 32) -------------
__global__ void k_transpose(const float* __restrict__ src, bf16* __restrict__ dst,
                            int R, int Cc, long strideSrc, long strideDst) {
    __shared__ bf16 tile[32][33];
    const long zb = blockIdx.z;
    src += zb * strideSrc;
    dst += zb * strideDst;
    int c0 = blockIdx.x * 32, r0 = blockIdx.y * 32;
    int tx = threadIdx.x & 31, ty = threadIdx.x >> 5;
    for (int i = ty; i < 32; i += 8)
        tile[i][tx] = f2bf(src[(long)(r0 + i) * Cc + (c0 + tx)]);
    __syncthreads();
    for (int i = ty; i < 32; i += 8)
        dst[(long)(c0 + i) * R + (r0 + tx)] = tile[tx][i];
}

// ---- fused: per-head transpose of Wq/Wk/Wv ([16][1024][64] -> [3072][1024] bf16)
//      + qkv bias pack piggyback (saves 3 launches vs separate kernels) ----------
__global__ void k_transpose3(const float* __restrict__ Wq, const float* __restrict__ Wk,
                             const float* __restrict__ Wv, const float* __restrict__ bqv,
                             const float* __restrict__ bkv, const float* __restrict__ bvv,
                             bf16* __restrict__ dst, float* __restrict__ bdst) {
    __shared__ bf16 tile[32][33];
    const int zb = blockIdx.z;  // 0..47
    const int which = zb >> 4, head = zb & 15;
    const float* src = (which == 0 ? Wq : which == 1 ? Wk : Wv) + (long)head * 65536;
    bf16* d = dst + (long)which * 1048576 + (long)head * 65536;
    int c0 = blockIdx.x * 32, r0 = blockIdx.y * 32;
    int tx = threadIdx.x & 31, ty = threadIdx.x >> 5;
    for (int i = ty; i < 32; i += 8)
        tile[i][tx] = f2bf(src[(long)(r0 + i) * 64 + (c0 + tx)]);
    if (blockIdx.x == 0 && blockIdx.y == 0 && zb < 12) {
        int i = zb * 256 + threadIdx.x;  // 0..3071
        bdst[i] = i < 1024 ? bqv[i] : i < 2048 ? bkv[i - 1024] : bvv[i - 2048];
    }
    __syncthreads();
    for (int i = ty; i < 32; i += 8)
        d[(long)(c0 + i) * 1024 + (r0 + tx)] = tile[tx][i];
}

// ---------------- LayerNorm over the SEQUENCE axis (per (b,c)), f32 in ----------
__global__ void k_ln_part(const float* __restrict__ x, float* __restrict__ ps,
                          float* __restrict__ pss) {
    int c = blockIdx.x * 256 + threadIdx.x;
    int b = blockIdx.y;
    int tc = blockIdx.z;  // 32 chunks of 64 timesteps
    const float* p = x + (long)b * Tq * Cq + (long)tc * 64 * Cq + c;
    float s = 0.f, ss = 0.f;
    for (int t = 0; t < 64; ++t) {
        float v = p[(long)t * Cq];
        s += v;
        ss += v * v;
    }
    long o = ((long)tc * Bq + b) * Cq + c;
    ps[o] = s;
    pss[o] = ss;
}

__global__ void k_ln_fin(const float* __restrict__ ps, const float* __restrict__ pss,
                         float* __restrict__ mean, float* __restrict__ rstd) {
    int i = blockIdx.x * 256 + threadIdx.x;  // b*Cq + c
    float s = 0.f, ss = 0.f;
    for (int tc = 0; tc < 32; ++tc) {
        s += ps[(long)tc * (Bq * Cq) + i];
        ss += pss[(long)tc * (Bq * Cq) + i];
    }
    float m = s / (float)Tq;
    float var = (ss - s * m) / (float)(Tq - 1);  // ddof=1 (unbiased)
    var = fmaxf(var, 0.f);
    mean[i] = m;
    rstd[i] = 1.0f / (sqrtf(var) + EPSq);  // eps OUTSIDE sqrt
}

__global__ void k_ln_apply(const float* __restrict__ x, const float* __restrict__ mean,
                           const float* __restrict__ rstd, const float* __restrict__ gamma,
                           const float* __restrict__ beta, bf16* __restrict__ out) {
    long i = (long)blockIdx.x * 256 + threadIdx.x;
    int c = (int)(i & (Cq - 1));
    long bt = i >> 10;
    int b = (int)(bt >> 11);
    float m = mean[b * Cq + c], r = rstd[b * Cq + c];
    out[i] = f2bf(gamma[c] * ((x[i] - m) * r) + beta[c]);
}

// XCD-aware bijective chunked swizzle (nwg % 8 == 0 for all our grids)
__device__ __forceinline__ void xcd_swizzle(int& bx, int& by) {
    const int gx = gridDim.x;
    const int nwg = gx * gridDim.y;
    const int bid = blockIdx.y * gx + blockIdx.x;
    const int swz = (bid & 7) * (nwg >> 3) + (bid >> 3);
    bx = swz % gx;
    by = swz / gx;
}

// ---------------- bf16 NT-GEMM, 128x128 tile, BK=64 (two BK=32 planes) ----------
// Conflict-free LDS read swizzle (verified r2: conflicts 6.3M -> 0).
// MODE 0: +bias, scatter qkv. MODE 2: relu(+bias) -> outB bf16 (FF1)
template <int MODE>
__global__ __launch_bounds__(256, 3) void k_gemm_nt(
    const bf16* __restrict__ A, int lda, const bf16* __restrict__ Bt, int ldb, int K,
    const float* __restrict__ bias, bf16* __restrict__ outB, int ldout) {
    __shared__ __bf16 sA[2][128 * 32];
    __shared__ __bf16 sB[2][128 * 32];
    int bx, by;
    xcd_swizzle(bx, by);
    const int m0 = by * 128, n0 = bx * 128;
    const int tid = threadIdx.x;
    const int lane = tid & 63, wave = tid >> 6;
    const int lane15 = lane & 15, quad = lane >> 4;
    const int wm = (wave >> 1) * 64, wn = (wave & 1) * 64;
    const int srow = wave * 16 + (lane >> 2);
    const int scol = (((lane & 3) ^ ((lane >> 3) & 3)) * 8);  // swizzled source slot
    const int sq8 = (quad ^ ((lane15 >> 1) & 3)) * 8;         // swizzled read slot
    __bf16* a00 = &sA[0][wave * 512];
    __bf16* a01 = &sA[0][2048 + wave * 512];
    __bf16* a10 = &sA[1][wave * 512];
    __bf16* a11 = &sA[1][2048 + wave * 512];
    __bf16* b00 = &sB[0][wave * 512];
    __bf16* b01 = &sB[0][2048 + wave * 512];
    __bf16* b10 = &sB[1][wave * 512];
    __bf16* b11 = &sB[1][2048 + wave * 512];
    const bf16* Ap = A + (long)(m0 + srow) * lda + scol;
    const bf16* Ap2 = Ap + 64L * lda;
    const bf16* Bp = Bt + (long)(n0 + srow) * ldb + scol;
    const bf16* Bp2 = Bp + 64L * ldb;

    f32x4 acc[4][4];
#pragma unroll
    for (int i = 0; i < 4; ++i)
#pragma unroll
        for (int j = 0; j < 4; ++j)
#pragma unroll
            for (int p = 0; p < 4; ++p) acc[i][j][p] = 0.f;

    for (int k0 = 0; k0 < K; k0 += 64) {
        __syncthreads();
        gload16(Ap + k0, a00);
        gload16(Ap2 + k0, a01);
        gload16(Ap + k0 + 32, a10);
        gload16(Ap2 + k0 + 32, a11);
        gload16(Bp + k0, b00);
        gload16(Bp2 + k0, b01);
        gload16(Bp + k0 + 32, b10);
        gload16(Bp2 + k0 + 32, b11);
        __syncthreads();
#pragma unroll
        for (int kk = 0; kk < 2; ++kk) {
            bf16x8 af[4], bfr[4];
#pragma unroll
            for (int i = 0; i < 4; ++i)
                af[i] = *(const bf16x8*)(&sA[kk][(wm + i * 16 + lane15) * 32 + sq8]);
#pragma unroll
            for (int j = 0; j < 4; ++j)
                bfr[j] = *(const bf16x8*)(&sB[kk][(wn + j * 16 + lane15) * 32 + sq8]);
#pragma unroll
            for (int i = 0; i < 4; ++i)
#pragma unroll
                for (int j = 0; j < 4; ++j)
                    acc[i][j] = __builtin_amdgcn_mfma_f32_16x16x32_bf16(af[i], bfr[j],
                                                                        acc[i][j], 0, 0, 0);
        }
    }
    // epilogue: C/D layout col=lane&15, row=quad*4+reg (m89/m91 verified)
    if (MODE == 0) {
#pragma unroll
        for (int i = 0; i < 4; ++i) {
            const int mm = m0 + wm + i * 16 + quad * 4;  // t base; p adds 0..3
            const int b = mm >> 11, t4 = mm & (Tq - 1);
#pragma unroll
            for (int j = 0; j < 4; ++j) {
                const int n = n0 + wn + j * 16 + lane15;
                const int which = n >> 10, hh = (n >> 6) & (Hq - 1), d = n & (HSq - 1);
                const long bh = (long)b * Hq + hh;
                const float bb = bias[n];
                if (which == 0) {  // q, pre-scaled by 1/8 (softmax scale folded in)
#pragma unroll
                    for (int p = 0; p < 4; ++p)
                        outB[bh * 131072 + (long)(t4 + p) * HSq + d] =
                            f2bf((acc[i][j][p] + bb) * 0.125f);
                } else if (which == 1) {  // k
#pragma unroll
                    for (int p = 0; p < 4; ++p)
                        outB[4194304L + bh * 131072 + (long)(t4 + p) * HSq + d] =
                            f2bf(acc[i][j][p] + bb);
                } else {  // V stored transposed [bh][d][t], 4 consecutive t packed
                    ushort4 pk;
                    pk.x = f2u(acc[i][j][0] + bb);
                    pk.y = f2u(acc[i][j][1] + bb);
                    pk.z = f2u(acc[i][j][2] + bb);
                    pk.w = f2u(acc[i][j][3] + bb);
                    *(ushort4*)(&outB[8388608L + bh * 131072 + (long)d * Tq + t4]) = pk;
                }
            }
        }
    } else {  // MODE 2: relu(+bias) -> bf16
#pragma unroll
        for (int i = 0; i < 4; ++i) {
#pragma unroll
            for (int p = 0; p < 4; ++p) {
                const int m = m0 + wm + i * 16 + quad * 4 + p;
#pragma unroll
                for (int j = 0; j < 4; ++j) {
                    const int n = n0 + wn + j * 16 + lane15;
                    outB[(long)m * ldout + n] = f2bf(fmaxf(acc[i][j][p] + bias[n], 0.f));
                }
            }
        }
    }
}

// ---------------- bf16 NT-GEMM, 128x64 tile, BK=64 (proj, FF2) ------------------
// 512 blocks = 2 blocks/CU cross-block overlap. MODE 1/3: outF = acc+bias+residF
template <int MODE>
__global__ __launch_bounds__(256, 4) void k_gemm_n64(
    const bf16* __restrict__ A, int lda, const bf16* __restrict__ Bt, int ldb, int K,
    const float* __restrict__ bias, const float* __restrict__ residF,
    float* __restrict__ outF, int ldout) {
    __shared__ __bf16 sA[2][128 * 32];
    __shared__ __bf16 sB[2][64 * 32];
    int bx, by;
    xcd_swizzle(bx, by);
    const int m0 = by * 128, n0 = bx * 64;
    const int tid = threadIdx.x;
    const int lane = tid & 63, wave = tid >> 6;
    const int lane15 = lane & 15, quad = lane >> 4;
    const int wm = wave * 32;
    const int srow = wave * 16 + (lane >> 2);
    const int scol = (((lane & 3) ^ ((lane >> 3) & 3)) * 8);
    const int sq8 = (quad ^ ((lane15 >> 1) & 3)) * 8;
    __bf16* a00 = &sA[0][wave * 512];
    __bf16* a01 = &sA[0][2048 + wave * 512];
    __bf16* a10 = &sA[1][wave * 512];
    __bf16* a11 = &sA[1][2048 + wave * 512];
    __bf16* b00 = &sB[0][wave * 512];
    __bf16* b10 = &sB[1][wave * 512];
    const bf16* Ap = A + (long)(m0 + srow) * lda + scol;
    const bf16* Ap2 = Ap + 64L * lda;
    const bf16* Bp = Bt + (long)(n0 + srow) * ldb + scol;

    f32x4 acc[2][4];
#pragma unroll
    for (int i = 0; i < 2; ++i)
#pragma unroll
        for (int j = 0; j < 4; ++j)
#pragma unroll
            for (int p = 0; p < 4; ++p) acc[i][j][p] = 0.f;

    for (int k0 = 0; k0 < K; k0 += 64) {
        __syncthreads();
        gload16(Ap + k0, a00);
        gload16(Ap2 + k0, a01);
        gload16(Ap + k0 + 32, a10);
        gload16(Ap2 + k0 + 32, a11);
        gload16(Bp + k0, b00);
        gload16(Bp + k0 + 32, b10);
        __syncthreads();
#pragma unroll
        for (int kk = 0; kk < 2; ++kk) {
            bf16x8 af[2], bfr[4];
#pragma unroll
            for (int i = 0; i < 2; ++i)
                af[i] = *(const bf16x8*)(&sA[kk][(wm + i * 16 + lane15) * 32 + sq8]);
#pragma unroll
            for (int j = 0; j < 4; ++j)
                bfr[j] = *(const bf16x8*)(&sB[kk][(j * 16 + lane15) * 32 + sq8]);
#pragma unroll
            for (int i = 0; i < 2; ++i)
#pragma unroll
                for (int j = 0; j < 4; ++j)
                    acc[i][j] = __builtin_amdgcn_mfma_f32_16x16x32_bf16(af[i], bfr[j],
                                                                        acc[i][j], 0, 0, 0);
        }
    }
#pragma unroll
    for (int i = 0; i < 2; ++i) {
#pragma unroll
        for (int p = 0; p < 4; ++p) {
            const int m = m0 + wm + i * 16 + quad * 4 + p;
#pragma unroll
            for (int j = 0; j < 4; ++j) {
                const int n = n0 + j * 16 + lane15;
                outF[(long)m * ldout + n] =
                    acc[i][j][p] + bias[n] + residF[(long)m * ldout + n];
            }
        }
    }
}

// ---------------- flash attention, kc-split x2 -----------------------------------
// Softmax has no running max (pure exp sums) -> the kc range splits associatively.
// grid (16, 32, 2): z = kc half. 1024 blocks = 4 blocks/CU = 4 waves/SIMD (was 2:
// grid-limited latency-bound kernel, VALUBusy 43% / MfmaUtil 22%, nothing
// saturated). Each half writes unnormalized partial O (f32) + partial row sums;
// k_attn_combine adds, normalizes, casts to bf16.
__global__ __launch_bounds__(256, 4) void k_attn(const bf16* __restrict__ qkv,
                                                 float* __restrict__ po0,
                                                 float* __restrict__ po1,
                                                 float* __restrict__ rs0,
                                                 float* __restrict__ rs1) {
    __shared__ __bf16 sK[64 * 72];
    __shared__ __bf16 sVt[64 * 72];
    const int bh = blockIdx.y;
    const int q0 = blockIdx.x * 128;
    const int z = blockIdx.z;
    const int kc0 = z << 10;
    float* __restrict__ po = z ? po1 : po0;
    float* __restrict__ rsb = z ? rs1 : rs0;
    const int tid = threadIdx.x, wave = tid >> 6, lane = tid & 63;
    const int lane31 = lane & 31, laneh = lane >> 5;
    const bf16* Qp = qkv + (long)bh * 131072;
    const bf16* Kp = qkv + 4194304L + (long)bh * 131072;
    const bf16* Vtp = qkv + 8388608L + (long)bh * 131072;
    bf16x8 qa[4];
#pragma unroll
    for (int s = 0; s < 4; ++s)
        qa[s] = *(const bf16x8*)(&Qp[(long)(q0 + wave * 32 + lane31) * HSq + s * 16 + laneh * 8]);
    f32x16 o[2];
#pragma unroll
    for (int dt = 0; dt < 2; ++dt)
#pragma unroll
        for (int r = 0; r < 16; ++r) o[dt][r] = 0.f;
    float rs = 0.f;
    const int r0 = tid >> 3, c0 = (tid & 7) * 8;
    const int r1 = r0 + 32;

    uint4 nk0 = *(const uint4*)(&Kp[(long)(kc0 + r0) * HSq + c0]);
    uint4 nk1 = *(const uint4*)(&Kp[(long)(kc0 + r1) * HSq + c0]);
    uint4 nv0 = *(const uint4*)(&Vtp[(long)r0 * Tq + kc0 + c0]);
    uint4 nv1 = *(const uint4*)(&Vtp[(long)r1 * Tq + kc0 + c0]);

    for (int kc = kc0; kc < kc0 + 1024; kc += 64) {
        __syncthreads();
        *(uint4*)(&sK[r0 * 72 + c0]) = nk0;
        *(uint4*)(&sK[r1 * 72 + c0]) = nk1;
        *(uint4*)(&sVt[r0 * 72 + c0]) = nv0;
        *(uint4*)(&sVt[r1 * 72 + c0]) = nv1;
        __syncthreads();
        if (kc + 64 < kc0 + 1024) {
            nk0 = *(const uint4*)(&Kp[(long)(kc + 64 + r0) * HSq + c0]);
            nk1 = *(const uint4*)(&Kp[(long)(kc + 64 + r1) * HSq + c0]);
            nv0 = *(const uint4*)(&Vtp[(long)r0 * Tq + kc + 64 + c0]);
            nv1 = *(const uint4*)(&Vtp[(long)r1 * Tq + kc + 64 + c0]);
        }
#pragma unroll
        for (int nt = 0; nt < 2; ++nt) {
            f32x16 zz;
#pragma unroll
            for (int r = 0; r < 16; ++r) zz[r] = 0.f;
            __builtin_amdgcn_s_setprio(1);
#pragma unroll
            for (int s = 0; s < 4; ++s) {
                bf16x8 kb =
                    *(const bf16x8*)(&sK[(nt * 32 + lane31) * 72 + s * 16 + laneh * 8]);
                zz = __builtin_amdgcn_mfma_f32_32x32x16_bf16(kb, qa[s], zz, 0, 0, 0);
            }
            __builtin_amdgcn_s_setprio(0);
            float e[16];
#pragma unroll
            for (int r = 0; r < 16; ++r) {
                e[r] = __expf(zz[r]);
                rs += e[r];
            }
            unsigned int pk[8];
#pragma unroll
            for (int g = 0; g < 4; ++g)
#pragma unroll
                for (int h = 0; h < 2; ++h)
                    pk[g * 2 + h] = (unsigned int)f2u(e[g * 4 + 2 * h]) |
                                    ((unsigned int)f2u(e[g * 4 + 2 * h + 1]) << 16);
            unsigned int sa0 = laneh ? pk[0] : pk[2], sa1 = laneh ? pk[1] : pk[3];
            unsigned int ra0 = __shfl_xor((int)sa0, 32), ra1 = __shfl_xor((int)sa1, 32);
            unsigned int sb0 = laneh ? pk[4] : pk[6], sb1 = laneh ? pk[5] : pk[7];
            unsigned int rb0 = __shfl_xor((int)sb0, 32), rb1 = __shfl_xor((int)sb1, 32);
            uint4 f0, f1;
            if (laneh == 0) {
                f0 = {pk[0], pk[1], ra0, ra1};
                f1 = {pk[4], pk[5], rb0, rb1};
            } else {
                f0 = {ra0, ra1, pk[2], pk[3]};
                f1 = {rb0, rb1, pk[6], pk[7]};
            }
            bf16x8 pa0 = __builtin_bit_cast(bf16x8, f0);
            bf16x8 pa1 = __builtin_bit_cast(bf16x8, f1);
            __builtin_amdgcn_s_setprio(1);
#pragma unroll
            for (int dt = 0; dt < 2; ++dt) {
                bf16x8 vb0 =
                    *(const bf16x8*)(&sVt[(dt * 32 + lane31) * 72 + nt * 32 + laneh * 8]);
                bf16x8 vb1 = *(const bf16x8*)(&sVt[(dt * 32 + lane31) * 72 + nt * 32 + 16 +
                                                   laneh * 8]);
                o[dt] = __builtin_amdgcn_mfma_f32_32x32x16_bf16(pa0, vb0, o[dt], 0, 0, 0);
                o[dt] = __builtin_amdgcn_mfma_f32_32x32x16_bf16(pa1, vb1, o[dt], 0, 0, 0);
            }
            __builtin_amdgcn_s_setprio(0);
        }
    }
    // partial epilogue: store unnormalized O (f32) + this half's row sums
    float ltot = rs + __shfl_xor(rs, 32);
    if (laneh == 0) rsb[(bh << 11) + q0 + wave * 32 + lane31] = ltot;
#pragma unroll
    for (int r = 0; r < 16; ++r) {
        const int tl = (r & 3) + 8 * (r >> 2) + 4 * laneh;
        const int t = q0 + wave * 32 + tl;
        float* pb = po + ((long)(bh << 11) + t) * 64;
#pragma unroll
        for (int dt = 0; dt < 2; ++dt) pb[dt * 32 + lane31] = o[dt][r];
    }
}

// combine: out[b][t][h*64+d] = bf16((po0+po1) / (rs0+rs1)) — 4 floats/thread
__global__ __launch_bounds__(256) void k_attn_combine(
    const float* __restrict__ po0, const float* __restrict__ po1,
    const float* __restrict__ rs0, const float* __restrict__ rs1,
    bf16* __restrict__ out) {
    const long i = ((long)blockIdx.x * 256 + threadIdx.x) * 4;
    const int d = (int)(i & 63);
    const long qq = i >> 6;  // bh*2048 + t
    const int bh = (int)(qq >> 11), t = (int)(qq & 2047);
    const float inv = 1.0f / (rs0[qq] + rs1[qq]);
    const f32x4 a = *(const f32x4*)(po0 + i);
    const f32x4 b = *(const f32x4*)(po1 + i);
    const int bb = bh >> 4, hh = bh & 15;
    ushort4 pk;
    pk.x = f2u((a[0] + b[0]) * inv);
    pk.y = f2u((a[1] + b[1]) * inv);
    pk.z = f2u((a[2] + b[2]) * inv);
    pk.w = f2u((a[3] + b[3]) * inv);
    *(ushort4*)(&out[(((long)bb * Tq + t) << 10) + hh * 64 + d]) = pk;
}

extern "C" void kernel_launch(void* const* d_in, const int* in_sizes, int n_in,
                              void* d_out, int out_size, void* d_ws, size_t ws_size,
                              hipStream_t stream) {
    const float* x = (const float*)d_in[0];
    const float* Wq = (const float*)d_in[1];
    const float* bqv = (const float*)d_in[2];
    const float* Wk = (const float*)d_in[3];
    const float* bkv = (const float*)d_in[4];
    const float* Wv = (const float*)d_in[5];
    const float* bvv = (const float*)d_in[6];
    const float* Wo = (const float*)d_in[7];
    const float* bo = (const float*)d_in[8];
    const float* W1 = (const float*)d_in[9];
    const float* b1 = (const float*)d_in[10];
    const float* W2 = (const float*)d_in[11];
    const float* b2 = (const float*)d_in[12];
    const float* g1 = (const float*)d_in[13];
    const float* be1 = (const float*)d_in[14];
    const float* g2 = (const float*)d_in[15];
    const float* be2 = (const float*)d_in[16];

    // ---- workspace: ~56.7 MiB total (safe under 64 MiB) ----
    char* ws = (char*)d_ws;
    size_t off = 0;
    auto alloc = [&](size_t bytes) {
        void* p = ws + off;
        off += (bytes + 255) & ~(size_t)255;
        return p;
    };
    bf16* regA = (bf16*)alloc(32L * 1024 * 1024);  // qkv (24 MiB)+attn_out tail, then a1 (32 MiB)
    float* x2 = (float*)alloc(4096L * 1024 * 4);   // 16 MiB: attn po0 scratch, then f32 residual
    bf16* buf1 = (bf16*)alloc(4096L * 1024 * 2);   // 8 MiB: WqkvT -> WoT -> W1T -> W2T
    float* bqkv = (float*)alloc(3072L * 4);
    float* ps = (float*)alloc(32L * Bq * Cq * 4);  // LN partials; attn rs0 scratch
    float* pss = (float*)alloc(32L * Bq * Cq * 4); // LN partials; attn rs1 scratch
    float* mean1 = (float*)alloc(Bq * Cq * 4);
    float* rstd1 = (float*)alloc(Bq * Cq * 4);
    float* mean2 = (float*)alloc(Bq * Cq * 4);
    float* rstd2 = (float*)alloc(Bq * Cq * 4);
    bf16* dres = (bf16*)d_out;          // d_out first 8 MiB bf16 scratch: h -> h2
    float* outF = (float*)d_out;
    float* po1 = (float*)d_out;         // full 16 MiB of d_out as attn po1 (h dead then)
    bf16* attn_out = regA + 12582912;   // 8 MiB free tail of regA (qkv uses 24 of 32 MiB)

    // LN1 -> h (bf16, in d_out)
    k_ln_part<<<dim3(4, Bq, 32), 256, 0, stream>>>(x, ps, pss);
    k_ln_fin<<<dim3(8), 256, 0, stream>>>(ps, pss, mean1, rstd1);
    k_ln_apply<<<dim3(16384), 256, 0, stream>>>(x, mean1, rstd1, g1, be1, dres);

    // Wq/Wk/Wv per-head transpose + bias pack (single launch)
    k_transpose3<<<dim3(2, 32, 48), 256, 0, stream>>>(Wq, Wk, Wv, bqv, bkv, bvv, buf1, bqkv);
    // QKV projection -> q(scaled),k,vt in regA
    k_gemm_nt<0><<<dim3(24, 32), 256, 0, stream>>>(dres, 1024, buf1, 1024, 1024, bqkv, regA, 0);
    // attention kc-split x2 -> partials (po0=x2, po1=d_out, rs in ps/pss)
    k_attn<<<dim3(16, 32, 2), 256, 0, stream>>>(regA, x2, po1, ps, pss);
    k_attn_combine<<<dim3(4096), 256, 0, stream>>>(x2, po1, ps, pss, attn_out);
    // Wo^T -> buf1; x2 = attn@Wo + bo + x   (128x64 tiles, 512 blocks, 2/CU)
    k_transpose<<<dim3(32, 32, 1), 256, 0, stream>>>(Wo, buf1, 1024, 1024, 0, 0);
    k_gemm_n64<1><<<dim3(16, 32), 256, 0, stream>>>(attn_out, 1024, buf1, 1024, 1024, bo, x,
                                                    x2, 1024);
    // LN2 -> h2 (bf16, in d_out; po1 dead)
    k_ln_part<<<dim3(4, Bq, 32), 256, 0, stream>>>(x2, ps, pss);
    k_ln_fin<<<dim3(8), 256, 0, stream>>>(ps, pss, mean2, rstd2);
    k_ln_apply<<<dim3(16384), 256, 0, stream>>>(x2, mean2, rstd2, g2, be2, dres);

    // ---- FF ----
    k_transpose<<<dim3(128, 32, 1), 256, 0, stream>>>(W1, buf1, 1024, 4096, 0, 0);  // W1T
    // a1 = relu(h2 @ W1T + b1) -> regA [4096][4096] bf16 (qkv+attn_out dead)
    k_gemm_nt<2><<<dim3(32, 32), 256, 0, stream>>>(dres, 1024, buf1, 1024, 1024, b1, regA, 4096);
    k_transpose<<<dim3(32, 128, 1), 256, 0, stream>>>(W2, buf1, 4096, 1024, 0, 0);  // W2T
    // d_out(f32) = a1 @ W2T + b2 + x2   (128x64 tiles, 512 blocks, 2/CU)
    k_gemm_n64<3><<<dim3(16, 32), 256, 0, stream>>>(regA, 4096, buf1, 4096, 4096, b2, x2, outF,
                                                    1024);
}

// Round 5
// 379.945 us; speedup vs baseline: 1.0970x; 1.0239x over previous
//
#include <hip/hip_runtime.h>
#include <hip/hip_bf16.h>

#define Bq 2
#define Tq 2048
#define Cq 1024
#define Hq 16
#define HSq 64
#define EPSq 1e-5f

using bf16 = __hip_bfloat16;
using f32x4 = __attribute__((ext_vector_type(4))) float;
using f32x16 = __attribute__((ext_vector_type(16))) float;
using bf16x8 = __attribute__((ext_vector_type(8))) __bf16;

__device__ __forceinline__ bf16 f2bf(float f) { return __float2bfloat16(f); }
__device__ __forceinline__ unsigned short f2u(float f) {
    return __builtin_bit_cast(unsigned short, __float2bfloat16(f));
}
// async global->LDS, 16B per lane; LDS dest = wave-uniform base + lane*16
__device__ __forceinline__ void gload16(const void* g, void* l) {
    __builtin_amdgcn_global_load_lds((const __attribute__((address_space(1))) void*)g,
                                     (__attribute__((address_space(3))) void*)l, 16, 0, 0);
}

// ------------- transpose f32 src -> bf16 dst (dims multiples of 32) -------------
__global__ void k_transpose(const float* __restrict__ src, bf16* __restrict__ dst,
                            int R, int Cc, long strideSrc, long strideDst) {
    __shared__ bf16 tile[32][33];
    const long zb = blockIdx.z;
    src += zb * strideSrc;
    dst += zb * strideDst;
    int c0 = blockIdx.x * 32, r0 = blockIdx.y * 32;
    int tx = threadIdx.x & 31, ty = threadIdx.x >> 5;
    for (int i = ty; i < 32; i += 8)
        tile[i][tx] = f2bf(src[(long)(r0 + i) * Cc + (c0 + tx)]);
    __syncthreads();
    for (int i = ty; i < 32; i += 8)
        dst[(long)(c0 + i) * R + (r0 + tx)] = tile[tx][i];
}

// ---- fused: per-head transpose of Wq/Wk/Wv ([16][1024][64] -> [3072][1024] bf16)
//      + qkv bias pack piggyback (saves 3 launches vs separate kernels) ----------
__global__ void k_transpose3(const float* __restrict__ Wq, const float* __restrict__ Wk,
                             const float* __restrict__ Wv, const float* __restrict__ bqv,
                             const float* __restrict__ bkv, const float* __restrict__ bvv,
                             bf16* __restrict__ dst, float* __restrict__ bdst) {
    __shared__ bf16 tile[32][33];
    const int zb = blockIdx.z;  // 0..47
    const int which = zb >> 4, head = zb & 15;
    const float* src = (which == 0 ? Wq : which == 1 ? Wk : Wv) + (long)head * 65536;
    bf16* d = dst + (long)which * 1048576 + (long)head * 65536;
    int c0 = blockIdx.x * 32, r0 = blockIdx.y * 32;
    int tx = threadIdx.x & 31, ty = threadIdx.x >> 5;
    for (int i = ty; i < 32; i += 8)
        tile[i][tx] = f2bf(src[(long)(r0 + i) * 64 + (c0 + tx)]);
    if (blockIdx.x == 0 && blockIdx.y == 0 && zb < 12) {
        int i = zb * 256 + threadIdx.x;  // 0..3071
        bdst[i] = i < 1024 ? bqv[i] : i < 2048 ? bkv[i - 1024] : bvv[i - 2048];
    }
    __syncthreads();
    for (int i = ty; i < 32; i += 8)
        d[(long)(c0 + i) * 1024 + (r0 + tx)] = tile[tx][i];
}

// ---------------- LayerNorm over the SEQUENCE axis (per (b,c)), f32 in ----------
__global__ void k_ln_part(const float* __restrict__ x, float* __restrict__ ps,
                          float* __restrict__ pss) {
    int c = blockIdx.x * 256 + threadIdx.x;
    int b = blockIdx.y;
    int tc = blockIdx.z;  // 32 chunks of 64 timesteps
    const float* p = x + (long)b * Tq * Cq + (long)tc * 64 * Cq + c;
    float s = 0.f, ss = 0.f;
    for (int t = 0; t < 64; ++t) {
        float v = p[(long)t * Cq];
        s += v;
        ss += v * v;
    }
    long o = ((long)tc * Bq + b) * Cq + c;
    ps[o] = s;
    pss[o] = ss;
}

__global__ void k_ln_fin(const float* __restrict__ ps, const float* __restrict__ pss,
                         float* __restrict__ mean, float* __restrict__ rstd) {
    int i = blockIdx.x * 256 + threadIdx.x;  // b*Cq + c
    float s = 0.f, ss = 0.f;
    for (int tc = 0; tc < 32; ++tc) {
        s += ps[(long)tc * (Bq * Cq) + i];
        ss += pss[(long)tc * (Bq * Cq) + i];
    }
    float m = s / (float)Tq;
    float var = (ss - s * m) / (float)(Tq - 1);  // ddof=1 (unbiased)
    var = fmaxf(var, 0.f);
    mean[i] = m;
    rstd[i] = 1.0f / (sqrtf(var) + EPSq);  // eps OUTSIDE sqrt
}

__global__ void k_ln_apply(const float* __restrict__ x, const float* __restrict__ mean,
                           const float* __restrict__ rstd, const float* __restrict__ gamma,
                           const float* __restrict__ beta, bf16* __restrict__ out) {
    long i = (long)blockIdx.x * 256 + threadIdx.x;
    int c = (int)(i & (Cq - 1));
    long bt = i >> 10;
    int b = (int)(bt >> 11);
    float m = mean[b * Cq + c], r = rstd[b * Cq + c];
    out[i] = f2bf(gamma[c] * ((x[i] - m) * r) + beta[c]);
}

// XCD-aware bijective chunked swizzle (nwg % 8 == 0 for all our grids)
__device__ __forceinline__ void xcd_swizzle(int& bx, int& by) {
    const int gx = gridDim.x;
    const int nwg = gx * gridDim.y;
    const int bid = blockIdx.y * gx + blockIdx.x;
    const int swz = (bid & 7) * (nwg >> 3) + (bid >> 3);
    bx = swz % gx;
    by = swz / gx;
}

// ---------------- bf16 NT-GEMM, 128x128 tile, BK=64 (two BK=32 planes) ----------
// Conflict-free LDS read swizzle (verified r2: conflicts 6.3M -> 0).
// MODE 0: +bias, scatter qkv. MODE 2: relu(+bias) -> outB bf16
template <int MODE>
__global__ __launch_bounds__(256, 3) void k_gemm_nt(
    const bf16* __restrict__ A, int lda, const bf16* __restrict__ Bt, int ldb, int K,
    const float* __restrict__ bias, bf16* __restrict__ outB, int ldout) {
    __shared__ __bf16 sA[2][128 * 32];
    __shared__ __bf16 sB[2][128 * 32];
    int bx, by;
    xcd_swizzle(bx, by);
    const int m0 = by * 128, n0 = bx * 128;
    const int tid = threadIdx.x;
    const int lane = tid & 63, wave = tid >> 6;
    const int lane15 = lane & 15, quad = lane >> 4;
    const int wm = (wave >> 1) * 64, wn = (wave & 1) * 64;
    const int srow = wave * 16 + (lane >> 2);
    const int scol = (((lane & 3) ^ ((lane >> 3) & 3)) * 8);  // swizzled source slot
    const int sq8 = (quad ^ ((lane15 >> 1) & 3)) * 8;         // swizzled read slot
    __bf16* a00 = &sA[0][wave * 512];
    __bf16* a01 = &sA[0][2048 + wave * 512];
    __bf16* a10 = &sA[1][wave * 512];
    __bf16* a11 = &sA[1][2048 + wave * 512];
    __bf16* b00 = &sB[0][wave * 512];
    __bf16* b01 = &sB[0][2048 + wave * 512];
    __bf16* b10 = &sB[1][wave * 512];
    __bf16* b11 = &sB[1][2048 + wave * 512];
    const bf16* Ap = A + (long)(m0 + srow) * lda + scol;
    const bf16* Ap2 = Ap + 64L * lda;
    const bf16* Bp = Bt + (long)(n0 + srow) * ldb + scol;
    const bf16* Bp2 = Bp + 64L * ldb;

    f32x4 acc[4][4];
#pragma unroll
    for (int i = 0; i < 4; ++i)
#pragma unroll
        for (int j = 0; j < 4; ++j)
#pragma unroll
            for (int p = 0; p < 4; ++p) acc[i][j][p] = 0.f;

    for (int k0 = 0; k0 < K; k0 += 64) {
        __syncthreads();
        gload16(Ap + k0, a00);
        gload16(Ap2 + k0, a01);
        gload16(Ap + k0 + 32, a10);
        gload16(Ap2 + k0 + 32, a11);
        gload16(Bp + k0, b00);
        gload16(Bp2 + k0, b01);
        gload16(Bp + k0 + 32, b10);
        gload16(Bp2 + k0 + 32, b11);
        __syncthreads();
#pragma unroll
        for (int kk = 0; kk < 2; ++kk) {
            bf16x8 af[4], bfr[4];
#pragma unroll
            for (int i = 0; i < 4; ++i)
                af[i] = *(const bf16x8*)(&sA[kk][(wm + i * 16 + lane15) * 32 + sq8]);
#pragma unroll
            for (int j = 0; j < 4; ++j)
                bfr[j] = *(const bf16x8*)(&sB[kk][(wn + j * 16 + lane15) * 32 + sq8]);
#pragma unroll
            for (int i = 0; i < 4; ++i)
#pragma unroll
                for (int j = 0; j < 4; ++j)
                    acc[i][j] = __builtin_amdgcn_mfma_f32_16x16x32_bf16(af[i], bfr[j],
                                                                        acc[i][j], 0, 0, 0);
        }
    }
    // epilogue: C/D layout col=lane&15, row=quad*4+reg (m89/m91 verified)
    if (MODE == 0) {
#pragma unroll
        for (int i = 0; i < 4; ++i) {
            const int mm = m0 + wm + i * 16 + quad * 4;  // t base; p adds 0..3
            const int b = mm >> 11, t4 = mm & (Tq - 1);
#pragma unroll
            for (int j = 0; j < 4; ++j) {
                const int n = n0 + wn + j * 16 + lane15;
                const int which = n >> 10, hh = (n >> 6) & (Hq - 1), d = n & (HSq - 1);
                const long bh = (long)b * Hq + hh;
                const float bb = bias[n];
                if (which == 0) {  // q, pre-scaled by 1/8 (softmax scale folded in)
#pragma unroll
                    for (int p = 0; p < 4; ++p)
                        outB[bh * 131072 + (long)(t4 + p) * HSq + d] =
                            f2bf((acc[i][j][p] + bb) * 0.125f);
                } else if (which == 1) {  // k
#pragma unroll
                    for (int p = 0; p < 4; ++p)
                        outB[4194304L + bh * 131072 + (long)(t4 + p) * HSq + d] =
                            f2bf(acc[i][j][p] + bb);
                } else {  // V stored transposed [bh][d][t], 4 consecutive t packed
                    ushort4 pk;
                    pk.x = f2u(acc[i][j][0] + bb);
                    pk.y = f2u(acc[i][j][1] + bb);
                    pk.z = f2u(acc[i][j][2] + bb);
                    pk.w = f2u(acc[i][j][3] + bb);
                    *(ushort4*)(&outB[8388608L + bh * 131072 + (long)d * Tq + t4]) = pk;
                }
            }
        }
    } else {  // MODE 2: relu(+bias) -> bf16
#pragma unroll
        for (int i = 0; i < 4; ++i) {
#pragma unroll
            for (int p = 0; p < 4; ++p) {
                const int m = m0 + wm + i * 16 + quad * 4 + p;
#pragma unroll
                for (int j = 0; j < 4; ++j) {
                    const int n = n0 + wn + j * 16 + lane15;
                    outB[(long)m * ldout + n] = f2bf(fmaxf(acc[i][j][p] + bias[n], 0.f));
                }
            }
        }
    }
}

// ---------------- bf16 NT-GEMM, 128x64 tile, BK=64 (proj, FF2) ------------------
// 512 blocks = 2 blocks/CU cross-block overlap. MODE 1/3: outF = acc+bias+residF
template <int MODE>
__global__ __launch_bounds__(256, 4) void k_gemm_n64(
    const bf16* __restrict__ A, int lda, const bf16* __restrict__ Bt, int ldb, int K,
    const float* __restrict__ bias, const float* __restrict__ residF,
    float* __restrict__ outF, int ldout) {
    __shared__ __bf16 sA[2][128 * 32];
    __shared__ __bf16 sB[2][64 * 32];
    int bx, by;
    xcd_swizzle(bx, by);
    const int m0 = by * 128, n0 = bx * 64;
    const int tid = threadIdx.x;
    const int lane = tid & 63, wave = tid >> 6;
    const int lane15 = lane & 15, quad = lane >> 4;
    const int wm = wave * 32;
    const int srow = wave * 16 + (lane >> 2);
    const int scol = (((lane & 3) ^ ((lane >> 3) & 3)) * 8);
    const int sq8 = (quad ^ ((lane15 >> 1) & 3)) * 8;
    __bf16* a00 = &sA[0][wave * 512];
    __bf16* a01 = &sA[0][2048 + wave * 512];
    __bf16* a10 = &sA[1][wave * 512];
    __bf16* a11 = &sA[1][2048 + wave * 512];
    __bf16* b00 = &sB[0][wave * 512];
    __bf16* b10 = &sB[1][wave * 512];
    const bf16* Ap = A + (long)(m0 + srow) * lda + scol;
    const bf16* Ap2 = Ap + 64L * lda;
    const bf16* Bp = Bt + (long)(n0 + srow) * ldb + scol;

    f32x4 acc[2][4];
#pragma unroll
    for (int i = 0; i < 2; ++i)
#pragma unroll
        for (int j = 0; j < 4; ++j)
#pragma unroll
            for (int p = 0; p < 4; ++p) acc[i][j][p] = 0.f;

    for (int k0 = 0; k0 < K; k0 += 64) {
        __syncthreads();
        gload16(Ap + k0, a00);
        gload16(Ap2 + k0, a01);
        gload16(Ap + k0 + 32, a10);
        gload16(Ap2 + k0 + 32, a11);
        gload16(Bp + k0, b00);
        gload16(Bp + k0 + 32, b10);
        __syncthreads();
#pragma unroll
        for (int kk = 0; kk < 2; ++kk) {
            bf16x8 af[2], bfr[4];
#pragma unroll
            for (int i = 0; i < 2; ++i)
                af[i] = *(const bf16x8*)(&sA[kk][(wm + i * 16 + lane15) * 32 + sq8]);
#pragma unroll
            for (int j = 0; j < 4; ++j)
                bfr[j] = *(const bf16x8*)(&sB[kk][(j * 16 + lane15) * 32 + sq8]);
#pragma unroll
            for (int i = 0; i < 2; ++i)
#pragma unroll
                for (int j = 0; j < 4; ++j)
                    acc[i][j] = __builtin_amdgcn_mfma_f32_16x16x32_bf16(af[i], bfr[j],
                                                                        acc[i][j], 0, 0, 0);
        }
    }
#pragma unroll
    for (int i = 0; i < 2; ++i) {
#pragma unroll
        for (int p = 0; p < 4; ++p) {
            const int m = m0 + wm + i * 16 + quad * 4 + p;
#pragma unroll
            for (int j = 0; j < 4; ++j) {
                const int n = n0 + j * 16 + lane15;
                outF[(long)m * ldout + n] =
                    acc[i][j][p] + bias[n] + residF[(long)m * ldout + n];
            }
        }
    }
}

// ======== 256x256 8-phase pipelined NT-GEMM (m201 template, plain HIP) ==========
// T3+T4+T5: per K-tile (BK=64) 4 phases of {ds_read subtile | stage 1 plane |
// barrier | 16 MFMA | barrier}; ONE counted s_waitcnt vmcnt(4) per K-tile (never
// 0 in the loop: 2 planes stay in flight across the barrier). LDS: 2 dbuf x 2
// planes[256][32] each for A and B = 128 KiB. 8 waves (2m x 4n), wave tile
// 128x64, acc 8x4 f32x4. Plane lifetime: stage lead-6 (ph0:A-kk1(t+1),
// ph1:B-kk1(t+1), ph2:A-kk0(t+2), ph3:B-kk0(t+2)); every overwrite lands >=1
// phase after the victim plane's last ds_read completes (reads retire at the
// consuming MFMA's lgkmcnt, which precedes the barrier the stage follows).
// vmcnt(4) at tile start guarantees planes 4t..4t+3 (the 8 oldest of <=12
// outstanding loads) have landed; all waves barrier after waiting -> cross-wave
// visibility. Same verified bank swizzle as k_gemm_nt (phys_slot = k8 ^
// ((row>>1)&3), both sides). Epilogue: relu(acc+bias) -> bf16 (FF1).
__global__ __launch_bounds__(512, 2) void k_gemm_8ph(
    const bf16* __restrict__ A, int lda, const bf16* __restrict__ Bt, int ldb, int K,
    const float* __restrict__ bias, bf16* __restrict__ outB, int ldout) {
    __shared__ __bf16 sA[2][2][256 * 32];
    __shared__ __bf16 sB[2][2][256 * 32];
    int bx, by;
    xcd_swizzle(bx, by);
    const int m0 = by * 256, n0 = bx * 256;
    const int tid = threadIdx.x;
    const int lane = tid & 63, wave = tid >> 6;
    const int lane15 = lane & 15, quad = lane >> 4;
    const int wr = wave >> 2, wc = wave & 3;  // wave tile: rows wr*128, cols wc*64
    const int sq8 = (quad ^ ((lane15 >> 1) & 3)) * 8;  // swizzled read slot
    const int arow = wr * 128 + lane15;
    const int brow = wc * 64 + lane15;
    const int sr = wave * 16 + (lane >> 2);                  // stage row (round 0)
    const int sc = ((lane & 3) ^ ((lane >> 3) & 3)) * 8;     // pre-swizzled src slot
    const bf16* ApS = A + (long)(m0 + sr) * lda + sc;
    const bf16* BpS = Bt + (long)(n0 + sr) * ldb + sc;
    const int NT = K >> 6;       // K-tiles
    const int NP = NT << 2;      // planes (4 per tile): 0=A-kk0,1=B-kk0,2=A-kk1,3=B-kk1

    auto stage_plane = [&](int q) {
        if (q >= NP) return;
        const int t = q >> 2, slot = q & 3;
        const int db = t & 1, kk = slot >> 1;
        const long ko = ((long)t << 6) + kk * 32;
        if (!(slot & 1)) {
            gload16(ApS + ko, &sA[db][kk][wave * 512]);
            gload16(ApS + ko + 128L * lda, &sA[db][kk][4096 + wave * 512]);
        } else {
            gload16(BpS + ko, &sB[db][kk][wave * 512]);
            gload16(BpS + ko + 128L * ldb, &sB[db][kk][4096 + wave * 512]);
        }
    };

    f32x4 acc[8][4];
#pragma unroll
    for (int i = 0; i < 8; ++i)
#pragma unroll
        for (int j = 0; j < 4; ++j)
#pragma unroll
            for (int p = 0; p < 4; ++p) acc[i][j][p] = 0.f;

    // prologue: tile 0 fully + tile 1 kk0 planes; drain tile 0 (8 loads), leave 4
    stage_plane(0);
    stage_plane(1);
    stage_plane(2);
    stage_plane(3);
    stage_plane(4);
    stage_plane(5);
    asm volatile("s_waitcnt vmcnt(4)" ::: "memory");
    __builtin_amdgcn_s_barrier();

    for (int t = 0; t < NT; ++t) {
        const int db = t & 1;
        const __bf16* A0 = sA[db][0];
        const __bf16* A1 = sA[db][1];
        const __bf16* B0 = sB[db][0];
        const __bf16* B1 = sB[db][1];
        bf16x8 af[4], bfx[4];
        // ---- phase 0: kk0, m-half 0 (reads B-kk0 + A-kk0 lo) ----
#pragma unroll
        for (int j = 0; j < 4; ++j)
            bfx[j] = *(const bf16x8*)(&B0[(brow + j * 16) * 32 + sq8]);
#pragma unroll
        for (int ii = 0; ii < 4; ++ii)
            af[ii] = *(const bf16x8*)(&A0[(arow + ii * 16) * 32 + sq8]);
        stage_plane(4 * t + 6);
        __builtin_amdgcn_s_barrier();
        __builtin_amdgcn_s_setprio(1);
#pragma unroll
        for (int ii = 0; ii < 4; ++ii)
#pragma unroll
            for (int j = 0; j < 4; ++j)
                acc[ii][j] =
                    __builtin_amdgcn_mfma_f32_16x16x32_bf16(af[ii], bfx[j], acc[ii][j], 0, 0, 0);
        __builtin_amdgcn_s_setprio(0);
        __builtin_amdgcn_s_barrier();
        // ---- phase 1: kk0, m-half 1 (B-kk0 reused from regs) ----
#pragma unroll
        for (int ii = 0; ii < 4; ++ii)
            af[ii] = *(const bf16x8*)(&A0[(arow + 64 + ii * 16) * 32 + sq8]);
        stage_plane(4 * t + 7);
        __builtin_amdgcn_s_barrier();
        __builtin_amdgcn_s_setprio(1);
#pragma unroll
        for (int ii = 0; ii < 4; ++ii)
#pragma unroll
            for (int j = 0; j < 4; ++j)
                acc[4 + ii][j] = __builtin_amdgcn_mfma_f32_16x16x32_bf16(af[ii], bfx[j],
                                                                         acc[4 + ii][j], 0, 0, 0);
        __builtin_amdgcn_s_setprio(0);
        __builtin_amdgcn_s_barrier();
        // ---- phase 2: kk1, m-half 0 (reads B-kk1 + A-kk1 lo) ----
#pragma unroll
        for (int j = 0; j < 4; ++j)
            bfx[j] = *(const bf16x8*)(&B1[(brow + j * 16) * 32 + sq8]);
#pragma unroll
        for (int ii = 0; ii < 4; ++ii)
            af[ii] = *(const bf16x8*)(&A1[(arow + ii * 16) * 32 + sq8]);
        stage_plane(4 * t + 8);
        __builtin_amdgcn_s_barrier();
        __builtin_amdgcn_s_setprio(1);
#pragma unroll
        for (int ii = 0; ii < 4; ++ii)
#pragma unroll
            for (int j = 0; j < 4; ++j)
                acc[ii][j] =
                    __builtin_amdgcn_mfma_f32_16x16x32_bf16(af[ii], bfx[j], acc[ii][j], 0, 0, 0);
        __builtin_amdgcn_s_setprio(0);
        __builtin_amdgcn_s_barrier();
        // ---- phase 3: kk1, m-half 1 ----
#pragma unroll
        for (int ii = 0; ii < 4; ++ii)
            af[ii] = *(const bf16x8*)(&A1[(arow + 64 + ii * 16) * 32 + sq8]);
        stage_plane(4 * t + 9);
        __builtin_amdgcn_s_barrier();
        __builtin_amdgcn_s_setprio(1);
#pragma unroll
        for (int ii = 0; ii < 4; ++ii)
#pragma unroll
            for (int j = 0; j < 4; ++j)
                acc[4 + ii][j] = __builtin_amdgcn_mfma_f32_16x16x32_bf16(af[ii], bfx[j],
                                                                         acc[4 + ii][j], 0, 0, 0);
        __builtin_amdgcn_s_setprio(0);
        // tile boundary: counted drain (next tile's 4 planes = the oldest 8 loads)
        asm volatile("s_waitcnt vmcnt(4)" ::: "memory");
        __builtin_amdgcn_s_barrier();
    }
    // epilogue: relu(acc + bias) -> bf16
#pragma unroll
    for (int i = 0; i < 8; ++i) {
#pragma unroll
        for (int p = 0; p < 4; ++p) {
            const int m = m0 + wr * 128 + i * 16 + quad * 4 + p;
#pragma unroll
            for (int j = 0; j < 4; ++j) {
                const int n = n0 + wc * 64 + j * 16 + lane15;
                outB[(long)m * ldout + n] = f2bf(fmaxf(acc[i][j][p] + bias[n], 0.f));
            }
        }
    }
}

// ---------------- flash attention, kc-split x2 -----------------------------------
__global__ __launch_bounds__(256, 4) void k_attn(const bf16* __restrict__ qkv,
                                                 float* __restrict__ po0,
                                                 float* __restrict__ po1,
                                                 float* __restrict__ rs0,
                                                 float* __restrict__ rs1) {
    __shared__ __bf16 sK[64 * 72];
    __shared__ __bf16 sVt[64 * 72];
    const int bh = blockIdx.y;
    const int q0 = blockIdx.x * 128;
    const int z = blockIdx.z;
    const int kc0 = z << 10;
    float* __restrict__ po = z ? po1 : po0;
    float* __restrict__ rsb = z ? rs1 : rs0;
    const int tid = threadIdx.x, wave = tid >> 6, lane = tid & 63;
    const int lane31 = lane & 31, laneh = lane >> 5;
    const bf16* Qp = qkv + (long)bh * 131072;
    const bf16* Kp = qkv + 4194304L + (long)bh * 131072;
    const bf16* Vtp = qkv + 8388608L + (long)bh * 131072;
    bf16x8 qa[4];
#pragma unroll
    for (int s = 0; s < 4; ++s)
        qa[s] = *(const bf16x8*)(&Qp[(long)(q0 + wave * 32 + lane31) * HSq + s * 16 + laneh * 8]);
    f32x16 o[2];
#pragma unroll
    for (int dt = 0; dt < 2; ++dt)
#pragma unroll
        for (int r = 0; r < 16; ++r) o[dt][r] = 0.f;
    float rs = 0.f;
    const int r0 = tid >> 3, c0 = (tid & 7) * 8;
    const int r1 = r0 + 32;

    uint4 nk0 = *(const uint4*)(&Kp[(long)(kc0 + r0) * HSq + c0]);
    uint4 nk1 = *(const uint4*)(&Kp[(long)(kc0 + r1) * HSq + c0]);
    uint4 nv0 = *(const uint4*)(&Vtp[(long)r0 * Tq + kc0 + c0]);
    uint4 nv1 = *(const uint4*)(&Vtp[(long)r1 * Tq + kc0 + c0]);

    for (int kc = kc0; kc < kc0 + 1024; kc += 64) {
        __syncthreads();
        *(uint4*)(&sK[r0 * 72 + c0]) = nk0;
        *(uint4*)(&sK[r1 * 72 + c0]) = nk1;
        *(uint4*)(&sVt[r0 * 72 + c0]) = nv0;
        *(uint4*)(&sVt[r1 * 72 + c0]) = nv1;
        __syncthreads();
        if (kc + 64 < kc0 + 1024) {
            nk0 = *(const uint4*)(&Kp[(long)(kc + 64 + r0) * HSq + c0]);
            nk1 = *(const uint4*)(&Kp[(long)(kc + 64 + r1) * HSq + c0]);
            nv0 = *(const uint4*)(&Vtp[(long)r0 * Tq + kc + 64 + c0]);
            nv1 = *(const uint4*)(&Vtp[(long)r1 * Tq + kc + 64 + c0]);
        }
#pragma unroll
        for (int nt = 0; nt < 2; ++nt) {
            f32x16 zz;
#pragma unroll
            for (int r = 0; r < 16; ++r) zz[r] = 0.f;
            __builtin_amdgcn_s_setprio(1);
#pragma unroll
            for (int s = 0; s < 4; ++s) {
                bf16x8 kb =
                    *(const bf16x8*)(&sK[(nt * 32 + lane31) * 72 + s * 16 + laneh * 8]);
                zz = __builtin_amdgcn_mfma_f32_32x32x16_bf16(kb, qa[s], zz, 0, 0, 0);
            }
            __builtin_amdgcn_s_setprio(0);
            float e[16];
#pragma unroll
            for (int r = 0; r < 16; ++r) {
                e[r] = __expf(zz[r]);
                rs += e[r];
            }
            unsigned int pk[8];
#pragma unroll
            for (int g = 0; g < 4; ++g)
#pragma unroll
                for (int h = 0; h < 2; ++h)
                    pk[g * 2 + h] = (unsigned int)f2u(e[g * 4 + 2 * h]) |
                                    ((unsigned int)f2u(e[g * 4 + 2 * h + 1]) << 16);
            unsigned int sa0 = laneh ? pk[0] : pk[2], sa1 = laneh ? pk[1] : pk[3];
            unsigned int ra0 = __shfl_xor((int)sa0, 32), ra1 = __shfl_xor((int)sa1, 32);
            unsigned int sb0 = laneh ? pk[4] : pk[6], sb1 = laneh ? pk[5] : pk[7];
            unsigned int rb0 = __shfl_xor((int)sb0, 32), rb1 = __shfl_xor((int)sb1, 32);
            uint4 f0, f1;
            if (laneh == 0) {
                f0 = {pk[0], pk[1], ra0, ra1};
                f1 = {pk[4], pk[5], rb0, rb1};
            } else {
                f0 = {ra0, ra1, pk[2], pk[3]};
                f1 = {rb0, rb1, pk[6], pk[7]};
            }
            bf16x8 pa0 = __builtin_bit_cast(bf16x8, f0);
            bf16x8 pa1 = __builtin_bit_cast(bf16x8, f1);
            __builtin_amdgcn_s_setprio(1);
#pragma unroll
            for (int dt = 0; dt < 2; ++dt) {
                bf16x8 vb0 =
                    *(const bf16x8*)(&sVt[(dt * 32 + lane31) * 72 + nt * 32 + laneh * 8]);
                bf16x8 vb1 = *(const bf16x8*)(&sVt[(dt * 32 + lane31) * 72 + nt * 32 + 16 +
                                                   laneh * 8]);
                o[dt] = __builtin_amdgcn_mfma_f32_32x32x16_bf16(pa0, vb0, o[dt], 0, 0, 0);
                o[dt] = __builtin_amdgcn_mfma_f32_32x32x16_bf16(pa1, vb1, o[dt], 0, 0, 0);
            }
            __builtin_amdgcn_s_setprio(0);
        }
    }
    // partial epilogue: store unnormalized O (f32) + this half's row sums
    float ltot = rs + __shfl_xor(rs, 32);
    if (laneh == 0) rsb[(bh << 11) + q0 + wave * 32 + lane31] = ltot;
#pragma unroll
    for (int r = 0; r < 16; ++r) {
        const int tl = (r & 3) + 8 * (r >> 2) + 4 * laneh;
        const int t = q0 + wave * 32 + tl;
        float* pb = po + ((long)(bh << 11) + t) * 64;
#pragma unroll
        for (int dt = 0; dt < 2; ++dt) pb[dt * 32 + lane31] = o[dt][r];
    }
}

// combine: out[b][t][h*64+d] = bf16((po0+po1) / (rs0+rs1)) — 4 floats/thread
__global__ __launch_bounds__(256) void k_attn_combine(
    const float* __restrict__ po0, const float* __restrict__ po1,
    const float* __restrict__ rs0, const float* __restrict__ rs1,
    bf16* __restrict__ out) {
    const long i = ((long)blockIdx.x * 256 + threadIdx.x) * 4;
    const int d = (int)(i & 63);
    const long qq = i >> 6;  // bh*2048 + t
    const int bh = (int)(qq >> 11), t = (int)(qq & 2047);
    const float inv = 1.0f / (rs0[qq] + rs1[qq]);
    const f32x4 a = *(const f32x4*)(po0 + i);
    const f32x4 b = *(const f32x4*)(po1 + i);
    const int bb = bh >> 4, hh = bh & 15;
    ushort4 pk;
    pk.x = f2u((a[0] + b[0]) * inv);
    pk.y = f2u((a[1] + b[1]) * inv);
    pk.z = f2u((a[2] + b[2]) * inv);
    pk.w = f2u((a[3] + b[3]) * inv);
    *(ushort4*)(&out[(((long)bb * Tq + t) << 10) + hh * 64 + d]) = pk;
}

extern "C" void kernel_launch(void* const* d_in, const int* in_sizes, int n_in,
                              void* d_out, int out_size, void* d_ws, size_t ws_size,
                              hipStream_t stream) {
    const float* x = (const float*)d_in[0];
    const float* Wq = (const float*)d_in[1];
    const float* bqv = (const float*)d_in[2];
    const float* Wk = (const float*)d_in[3];
    const float* bkv = (const float*)d_in[4];
    const float* Wv = (const float*)d_in[5];
    const float* bvv = (const float*)d_in[6];
    const float* Wo = (const float*)d_in[7];
    const float* bo = (const float*)d_in[8];
    const float* W1 = (const float*)d_in[9];
    const float* b1 = (const float*)d_in[10];
    const float* W2 = (const float*)d_in[11];
    const float* b2 = (const float*)d_in[12];
    const float* g1 = (const float*)d_in[13];
    const float* be1 = (const float*)d_in[14];
    const float* g2 = (const float*)d_in[15];
    const float* be2 = (const float*)d_in[16];

    // ---- workspace: ~56.7 MiB total (safe under 64 MiB) ----
    char* ws = (char*)d_ws;
    size_t off = 0;
    auto alloc = [&](size_t bytes) {
        void* p = ws + off;
        off += (bytes + 255) & ~(size_t)255;
        return p;
    };
    bf16* regA = (bf16*)alloc(32L * 1024 * 1024);  // qkv (24 MiB)+attn_out tail, then a1 (32 MiB)
    float* x2 = (float*)alloc(4096L * 1024 * 4);   // 16 MiB: attn po0 scratch, then f32 residual
    bf16* buf1 = (bf16*)alloc(4096L * 1024 * 2);   // 8 MiB: WqkvT -> WoT -> W1T -> W2T
    float* bqkv = (float*)alloc(3072L * 4);
    float* ps = (float*)alloc(32L * Bq * Cq * 4);  // LN partials; attn rs0 scratch
    float* pss = (float*)alloc(32L * Bq * Cq * 4); // LN partials; attn rs1 scratch
    float* mean1 = (float*)alloc(Bq * Cq * 4);
    float* rstd1 = (float*)alloc(Bq * Cq * 4);
    float* mean2 = (float*)alloc(Bq * Cq * 4);
    float* rstd2 = (float*)alloc(Bq * Cq * 4);
    bf16* dres = (bf16*)d_out;          // d_out first 8 MiB bf16 scratch: h -> h2
    float* outF = (float*)d_out;
    float* po1 = (float*)d_out;         // full 16 MiB of d_out as attn po1 (h dead then)
    bf16* attn_out = regA + 12582912;   // 8 MiB free tail of regA (qkv uses 24 of 32 MiB)

    // LN1 -> h (bf16, in d_out)
    k_ln_part<<<dim3(4, Bq, 32), 256, 0, stream>>>(x, ps, pss);
    k_ln_fin<<<dim3(8), 256, 0, stream>>>(ps, pss, mean1, rstd1);
    k_ln_apply<<<dim3(16384), 256, 0, stream>>>(x, mean1, rstd1, g1, be1, dres);

    // Wq/Wk/Wv per-head transpose + bias pack (single launch)
    k_transpose3<<<dim3(2, 32, 48), 256, 0, stream>>>(Wq, Wk, Wv, bqv, bkv, bvv, buf1, bqkv);
    // QKV projection -> q(scaled),k,vt in regA
    k_gemm_nt<0><<<dim3(24, 32), 256, 0, stream>>>(dres, 1024, buf1, 1024, 1024, bqkv, regA, 0);
    // attention kc-split x2 -> partials (po0=x2, po1=d_out, rs in ps/pss)
    k_attn<<<dim3(16, 32, 2), 256, 0, stream>>>(regA, x2, po1, ps, pss);
    k_attn_combine<<<dim3(4096), 256, 0, stream>>>(x2, po1, ps, pss, attn_out);
    // Wo^T -> buf1; x2 = attn@Wo + bo + x   (128x64 tiles, 512 blocks, 2/CU)
    k_transpose<<<dim3(32, 32, 1), 256, 0, stream>>>(Wo, buf1, 1024, 1024, 0, 0);
    k_gemm_n64<1><<<dim3(16, 32), 256, 0, stream>>>(attn_out, 1024, buf1, 1024, 1024, bo, x,
                                                    x2, 1024);
    // LN2 -> h2 (bf16, in d_out; po1 dead)
    k_ln_part<<<dim3(4, Bq, 32), 256, 0, stream>>>(x2, ps, pss);
    k_ln_fin<<<dim3(8), 256, 0, stream>>>(ps, pss, mean2, rstd2);
    k_ln_apply<<<dim3(16384), 256, 0, stream>>>(x2, mean2, rstd2, g2, be2, dres);

    // ---- FF ----
    k_transpose<<<dim3(128, 32, 1), 256, 0, stream>>>(W1, buf1, 1024, 4096, 0, 0);  // W1T
    // a1 = relu(h2 @ W1T + b1) -> regA [4096][4096] bf16  (8-phase 256^2 pipeline)
    k_gemm_8ph<<<dim3(16, 16), 512, 0, stream>>>(dres, 1024, buf1, 1024, 1024, b1, regA, 4096);
    k_transpose<<<dim3(32, 128, 1), 256, 0, stream>>>(W2, buf1, 4096, 1024, 0, 0);  // W2T
    // d_out(f32) = a1 @ W2T + b2 + x2   (128x64 tiles, 512 blocks, 2/CU)
    k_gemm_n64<3><<<dim3(16, 32), 256, 0, stream>>>(regA, 4096, buf1, 4096, 4096, b2, x2, outF,
                                                    1024);
}

// Round 7
// 369.167 us; speedup vs baseline: 1.1290x; 1.0292x over previous
//
#include <hip/hip_runtime.h>
#include <hip/hip_bf16.h>

#define Bq 2
#define Tq 2048
#define Cq 1024
#define Hq 16
#define HSq 64
#define EPSq 1e-5f

using bf16 = __hip_bfloat16;
using f32x4 = __attribute__((ext_vector_type(4))) float;
using f32x16 = __attribute__((ext_vector_type(16))) float;
using bf16x8 = __attribute__((ext_vector_type(8))) __bf16;

__device__ __forceinline__ bf16 f2bf(float f) { return __float2bfloat16(f); }
__device__ __forceinline__ unsigned short f2u(float f) {
    return __builtin_bit_cast(unsigned short, __float2bfloat16(f));
}
// async global->LDS, 16B per lane; LDS dest = wave-uniform base + lane*16
__device__ __forceinline__ void gload16(const void* g, void* l) {
    __builtin_amdgcn_global_load_lds((const __attribute__((address_space(1))) void*)g,
                                     (__attribute__((address_space(3))) void*)l, 16, 0, 0);
}

// ------------- transpose f32 src -> bf16 dst (dims multiples of 32) -------------
__global__ void k_transpose(const float* __restrict__ src, bf16* __restrict__ dst,
                            int R, int Cc, long strideSrc, long strideDst) {
    __shared__ bf16 tile[32][33];
    const long zb = blockIdx.z;
    src += zb * strideSrc;
    dst += zb * strideDst;
    int c0 = blockIdx.x * 32, r0 = blockIdx.y * 32;
    int tx = threadIdx.x & 31, ty = threadIdx.x >> 5;
    for (int i = ty; i < 32; i += 8)
        tile[i][tx] = f2bf(src[(long)(r0 + i) * Cc + (c0 + tx)]);
    __syncthreads();
    for (int i = ty; i < 32; i += 8)
        dst[(long)(c0 + i) * R + (r0 + tx)] = tile[tx][i];
}

// ---- fused: per-head transpose of Wq/Wk/Wv ([16][1024][64] -> [3072][1024] bf16)
//      + qkv bias pack piggyback ----------
__global__ void k_transpose3(const float* __restrict__ Wq, const float* __restrict__ Wk,
                             const float* __restrict__ Wv, const float* __restrict__ bqv,
                             const float* __restrict__ bkv, const float* __restrict__ bvv,
                             bf16* __restrict__ dst, float* __restrict__ bdst) {
    __shared__ bf16 tile[32][33];
    const int zb = blockIdx.z;  // 0..47
    const int which = zb >> 4, head = zb & 15;
    const float* src = (which == 0 ? Wq : which == 1 ? Wk : Wv) + (long)head * 65536;
    bf16* d = dst + (long)which * 1048576 + (long)head * 65536;
    int c0 = blockIdx.x * 32, r0 = blockIdx.y * 32;
    int tx = threadIdx.x & 31, ty = threadIdx.x >> 5;
    for (int i = ty; i < 32; i += 8)
        tile[i][tx] = f2bf(src[(long)(r0 + i) * 64 + (c0 + tx)]);
    if (blockIdx.x == 0 && blockIdx.y == 0 && zb < 12) {
        int i = zb * 256 + threadIdx.x;  // 0..3071
        bdst[i] = i < 1024 ? bqv[i] : i < 2048 ? bkv[i - 1024] : bvv[i - 2048];
    }
    __syncthreads();
    for (int i = ty; i < 32; i += 8)
        d[(long)(c0 + i) * 1024 + (r0 + tx)] = tile[tx][i];
}

// ---------------- LayerNorm over the SEQUENCE axis (per (b,c)), f32 in ----------
__global__ void k_ln_part(const float* __restrict__ x, float* __restrict__ ps,
                          float* __restrict__ pss) {
    int c = blockIdx.x * 256 + threadIdx.x;
    int b = blockIdx.y;
    int tc = blockIdx.z;  // 32 chunks of 64 timesteps
    const float* p = x + (long)b * Tq * Cq + (long)tc * 64 * Cq + c;
    float s = 0.f, ss = 0.f;
    for (int t = 0; t < 64; ++t) {
        float v = p[(long)t * Cq];
        s += v;
        ss += v * v;
    }
    long o = ((long)tc * Bq + b) * Cq + c;
    ps[o] = s;
    pss[o] = ss;
}

__global__ void k_ln_fin(const float* __restrict__ ps, const float* __restrict__ pss,
                         float* __restrict__ mean, float* __restrict__ rstd) {
    int i = blockIdx.x * 256 + threadIdx.x;  // b*Cq + c
    float s = 0.f, ss = 0.f;
    for (int tc = 0; tc < 32; ++tc) {
        s += ps[(long)tc * (Bq * Cq) + i];
        ss += pss[(long)tc * (Bq * Cq) + i];
    }
    float m = s / (float)Tq;
    float var = (ss - s * m) / (float)(Tq - 1);  // ddof=1 (unbiased)
    var = fmaxf(var, 0.f);
    mean[i] = m;
    rstd[i] = 1.0f / (sqrtf(var) + EPSq);  // eps OUTSIDE sqrt
}

__global__ void k_ln_apply(const float* __restrict__ x, const float* __restrict__ mean,
                           const float* __restrict__ rstd, const float* __restrict__ gamma,
                           const float* __restrict__ beta, bf16* __restrict__ out) {
    long i = (long)blockIdx.x * 256 + threadIdx.x;
    int c = (int)(i & (Cq - 1));
    long bt = i >> 10;
    int b = (int)(bt >> 11);
    float m = mean[b * Cq + c], r = rstd[b * Cq + c];
    out[i] = f2bf(gamma[c] * ((x[i] - m) * r) + beta[c]);
}

// XCD-aware bijective chunked swizzle (nwg % 8 == 0 for all our grids)
__device__ __forceinline__ void xcd_swizzle(int& bx, int& by) {
    const int gx = gridDim.x;
    const int nwg = gx * gridDim.y;
    const int bid = blockIdx.y * gx + blockIdx.x;
    const int swz = (bid & 7) * (nwg >> 3) + (bid >> 3);
    bx = swz % gx;
    by = swz / gx;
}

// ---------------- bf16 NT-GEMM, 128x128 tile, BK=64 (two BK=32 planes) ----------
// Conflict-free LDS read swizzle (verified r2: conflicts 6.3M -> 0).
// MODE 0: +bias, scatter qkv. MODE 2: relu(+bias) -> outB bf16
template <int MODE>
__global__ __launch_bounds__(256, 3) void k_gemm_nt(
    const bf16* __restrict__ A, int lda, const bf16* __restrict__ Bt, int ldb, int K,
    const float* __restrict__ bias, bf16* __restrict__ outB, int ldout) {
    __shared__ __bf16 sA[2][128 * 32];
    __shared__ __bf16 sB[2][128 * 32];
    int bx, by;
    xcd_swizzle(bx, by);
    const int m0 = by * 128, n0 = bx * 128;
    const int tid = threadIdx.x;
    const int lane = tid & 63, wave = tid >> 6;
    const int lane15 = lane & 15, quad = lane >> 4;
    const int wm = (wave >> 1) * 64, wn = (wave & 1) * 64;
    const int srow = wave * 16 + (lane >> 2);
    const int scol = (((lane & 3) ^ ((lane >> 3) & 3)) * 8);  // swizzled source slot
    const int sq8 = (quad ^ ((lane15 >> 1) & 3)) * 8;         // swizzled read slot
    __bf16* a00 = &sA[0][wave * 512];
    __bf16* a01 = &sA[0][2048 + wave * 512];
    __bf16* a10 = &sA[1][wave * 512];
    __bf16* a11 = &sA[1][2048 + wave * 512];
    __bf16* b00 = &sB[0][wave * 512];
    __bf16* b01 = &sB[0][2048 + wave * 512];
    __bf16* b10 = &sB[1][wave * 512];
    __bf16* b11 = &sB[1][2048 + wave * 512];
    const bf16* Ap = A + (long)(m0 + srow) * lda + scol;
    const bf16* Ap2 = Ap + 64L * lda;
    const bf16* Bp = Bt + (long)(n0 + srow) * ldb + scol;
    const bf16* Bp2 = Bp + 64L * ldb;

    f32x4 acc[4][4];
#pragma unroll
    for (int i = 0; i < 4; ++i)
#pragma unroll
        for (int j = 0; j < 4; ++j)
#pragma unroll
            for (int p = 0; p < 4; ++p) acc[i][j][p] = 0.f;

    for (int k0 = 0; k0 < K; k0 += 64) {
        __syncthreads();
        gload16(Ap + k0, a00);
        gload16(Ap2 + k0, a01);
        gload16(Ap + k0 + 32, a10);
        gload16(Ap2 + k0 + 32, a11);
        gload16(Bp + k0, b00);
        gload16(Bp2 + k0, b01);
        gload16(Bp + k0 + 32, b10);
        gload16(Bp2 + k0 + 32, b11);
        __syncthreads();
#pragma unroll
        for (int kk = 0; kk < 2; ++kk) {
            bf16x8 af[4], bfr[4];
#pragma unroll
            for (int i = 0; i < 4; ++i)
                af[i] = *(const bf16x8*)(&sA[kk][(wm + i * 16 + lane15) * 32 + sq8]);
#pragma unroll
            for (int j = 0; j < 4; ++j)
                bfr[j] = *(const bf16x8*)(&sB[kk][(wn + j * 16 + lane15) * 32 + sq8]);
#pragma unroll
            for (int i = 0; i < 4; ++i)
#pragma unroll
                for (int j = 0; j < 4; ++j)
                    acc[i][j] = __builtin_amdgcn_mfma_f32_16x16x32_bf16(af[i], bfr[j],
                                                                        acc[i][j], 0, 0, 0);
        }
    }
    // epilogue: C/D layout col=lane&15, row=quad*4+reg (m89/m91 verified)
    if (MODE == 0) {
#pragma unroll
        for (int i = 0; i < 4; ++i) {
            const int mm = m0 + wm + i * 16 + quad * 4;  // t base; p adds 0..3
            const int b = mm >> 11, t4 = mm & (Tq - 1);
#pragma unroll
            for (int j = 0; j < 4; ++j) {
                const int n = n0 + wn + j * 16 + lane15;
                const int which = n >> 10, hh = (n >> 6) & (Hq - 1), d = n & (HSq - 1);
                const long bh = (long)b * Hq + hh;
                const float bb = bias[n];
                if (which == 0) {  // q, pre-scaled by 1/8 (softmax scale folded in)
#pragma unroll
                    for (int p = 0; p < 4; ++p)
                        outB[bh * 131072 + (long)(t4 + p) * HSq + d] =
                            f2bf((acc[i][j][p] + bb) * 0.125f);
                } else if (which == 1) {  // k
#pragma unroll
                    for (int p = 0; p < 4; ++p)
                        outB[4194304L + bh * 131072 + (long)(t4 + p) * HSq + d] =
                            f2bf(acc[i][j][p] + bb);
                } else {  // V stored transposed [bh][d][t], 4 consecutive t packed
                    ushort4 pk;
                    pk.x = f2u(acc[i][j][0] + bb);
                    pk.y = f2u(acc[i][j][1] + bb);
                    pk.z = f2u(acc[i][j][2] + bb);
                    pk.w = f2u(acc[i][j][3] + bb);
                    *(ushort4*)(&outB[8388608L + bh * 131072 + (long)d * Tq + t4]) = pk;
                }
            }
        }
    } else {  // MODE 2: relu(+bias) -> bf16
#pragma unroll
        for (int i = 0; i < 4; ++i) {
#pragma unroll
            for (int p = 0; p < 4; ++p) {
                const int m = m0 + wm + i * 16 + quad * 4 + p;
#pragma unroll
                for (int j = 0; j < 4; ++j) {
                    const int n = n0 + wn + j * 16 + lane15;
                    outB[(long)m * ldout + n] = f2bf(fmaxf(acc[i][j][p] + bias[n], 0.f));
                }
            }
        }
    }
}

// ======= bf16 NT-GEMM 128x64, 2-deep counted-vmcnt pipeline (proj, FF2) =========
// T3/T4 applied to the n64 structure: 3 LDS buffers (24 KiB each = 72 KiB ->
// still 2 blocks/CU), stage(t+2) issued right after the barrier, ONE counted
// s_waitcnt vmcnt(6) per K-step (tile t+1's 6 loads stay in flight across the
// barrier; never vmcnt(0) in the loop). Tile T's loads issued at iter T-2 get
// ~1.5 steps (>600cy) to land vs the old serial structure's fully-exposed drain
// (measured 2290 cy/step vs ~300 cy of work, MfmaUtil 22%).
// Buffer layout (elements): A-kk0 [0,4096) rows0-127, A-kk1 [4096,8192),
// B-kk0 [8192,10240), B-kk1 [10240,12288).
// Overwrite hazard: stage(t+2) targets buf(t-1), last read in comp(t-1) which
// precedes the barrier every wave passed before any stage(t+2) issues.
// vmcnt trace (NT>=2): steady outstanding 12 -> wait 6 retires oldest tile;
// peeled last iter waits 0. MODE 1/3: outF = acc + bias + residF (f32).
template <int MODE>
__global__ __launch_bounds__(256, 2) void k_gemm_n64p(
    const bf16* __restrict__ A, int lda, const bf16* __restrict__ Bt, int ldb, int K,
    const float* __restrict__ bias, const float* __restrict__ residF,
    float* __restrict__ outF, int ldout) {
    __shared__ __bf16 lds[36864];  // 3 x 12288 (72 KiB)
    int bx, by;
    xcd_swizzle(bx, by);
    const int m0 = by * 128, n0 = bx * 64;
    const int tid = threadIdx.x;
    const int lane = tid & 63, wave = tid >> 6;
    const int lane15 = lane & 15, quad = lane >> 4;
    const int wm = wave * 32;
    const int srow = wave * 16 + (lane >> 2);
    const int scol = (((lane & 3) ^ ((lane >> 3) & 3)) * 8);  // pre-swizzled source
    const int sq8 = (quad ^ ((lane15 >> 1) & 3)) * 8;         // swizzled read slot
    const bf16* Ap = A + (long)(m0 + srow) * lda + scol;
    const bf16* Ap2 = Ap + 64L * lda;
    const bf16* Bp = Bt + (long)(n0 + srow) * ldb + scol;
    const int NT = K >> 6;

    f32x4 acc[2][4];
#pragma unroll
    for (int i = 0; i < 2; ++i)
#pragma unroll
        for (int j = 0; j < 4; ++j)
#pragma unroll
            for (int p = 0; p < 4; ++p) acc[i][j][p] = 0.f;

    auto stage = [&](int t, int ofs) {
        const long ko = (long)t << 6;
        __bf16* b = &lds[ofs + wave * 512];
        gload16(Ap + ko, b);              // A kk0 rows 0-63
        gload16(Ap2 + ko, b + 2048);      // A kk0 rows 64-127
        gload16(Ap + ko + 32, b + 4096);  // A kk1 rows 0-63
        gload16(Ap2 + ko + 32, b + 6144); // A kk1 rows 64-127
        gload16(Bp + ko, b + 8192);       // B kk0
        gload16(Bp + ko + 32, b + 10240); // B kk1
    };
    auto comp = [&](int ofs) {
        const __bf16* base = &lds[ofs];
#pragma unroll
        for (int kk = 0; kk < 2; ++kk) {
            bf16x8 af[2], bfr[4];
#pragma unroll
            for (int i = 0; i < 2; ++i)
                af[i] = *(const bf16x8*)(base + kk * 4096 + (wm + i * 16 + lane15) * 32 + sq8);
#pragma unroll
            for (int j = 0; j < 4; ++j)
                bfr[j] =
                    *(const bf16x8*)(base + 8192 + kk * 2048 + (j * 16 + lane15) * 32 + sq8);
#pragma unroll
            for (int i = 0; i < 2; ++i)
#pragma unroll
                for (int j = 0; j < 4; ++j)
                    acc[i][j] = __builtin_amdgcn_mfma_f32_16x16x32_bf16(af[i], bfr[j],
                                                                        acc[i][j], 0, 0, 0);
        }
    };

    stage(0, 0);
    stage(1, 12288);
    int o0 = 0, o1 = 12288, o2 = 24576;  // cur / next / staging target
    for (int t = 0; t < NT - 1; ++t) {
        asm volatile("s_waitcnt vmcnt(6)" ::: "memory");  // tile t landed (all 6)
        __builtin_amdgcn_s_barrier();
        if (t + 2 < NT) stage(t + 2, o2);  // issue early: hides under comp(t)+comp(t+1)
        comp(o0);
        const int tmp = o0;
        o0 = o1;
        o1 = o2;
        o2 = tmp;
    }
    asm volatile("s_waitcnt vmcnt(0)" ::: "memory");  // last tile
    __builtin_amdgcn_s_barrier();
    comp(o0);

#pragma unroll
    for (int i = 0; i < 2; ++i) {
#pragma unroll
        for (int p = 0; p < 4; ++p) {
            const int m = m0 + wm + i * 16 + quad * 4 + p;
#pragma unroll
            for (int j = 0; j < 4; ++j) {
                const int n = n0 + j * 16 + lane15;
                outF[(long)m * ldout + n] =
                    acc[i][j][p] + bias[n] + residF[(long)m * ldout + n];
            }
        }
    }
}

// ======== 256x256 8-phase pipelined NT-GEMM (m201 template, plain HIP) ==========
// Verified r5: passed, FF1 ~36us. T3+T4+T5; counted vmcnt(4) per K-tile.
__global__ __launch_bounds__(512, 2) void k_gemm_8ph(
    const bf16* __restrict__ A, int lda, const bf16* __restrict__ Bt, int ldb, int K,
    const float* __restrict__ bias, bf16* __restrict__ outB, int ldout) {
    __shared__ __bf16 sA[2][2][256 * 32];
    __shared__ __bf16 sB[2][2][256 * 32];
    int bx, by;
    xcd_swizzle(bx, by);
    const int m0 = by * 256, n0 = bx * 256;
    const int tid = threadIdx.x;
    const int lane = tid & 63, wave = tid >> 6;
    const int lane15 = lane & 15, quad = lane >> 4;
    const int wr = wave >> 2, wc = wave & 3;  // wave tile: rows wr*128, cols wc*64
    const int sq8 = (quad ^ ((lane15 >> 1) & 3)) * 8;  // swizzled read slot
    const int arow = wr * 128 + lane15;
    const int brow = wc * 64 + lane15;
    const int sr = wave * 16 + (lane >> 2);                  // stage row
    const int sc = ((lane & 3) ^ ((lane >> 3) & 3)) * 8;     // pre-swizzled src slot
    const bf16* ApS = A + (long)(m0 + sr) * lda + sc;
    const bf16* BpS = Bt + (long)(n0 + sr) * ldb + sc;
    const int NT = K >> 6;       // K-tiles
    const int NP = NT << 2;      // planes (4 per tile): 0=A-kk0,1=B-kk0,2=A-kk1,3=B-kk1

    auto stage_plane = [&](int q) {
        if (q >= NP) return;
        const int t = q >> 2, slot = q & 3;
        const int db = t & 1, kk = slot >> 1;
        const long ko = ((long)t << 6) + kk * 32;
        if (!(slot & 1)) {
            gload16(ApS + ko, &sA[db][kk][wave * 512]);
            gload16(ApS + ko + 128L * lda, &sA[db][kk][4096 + wave * 512]);
        } else {
            gload16(BpS + ko, &sB[db][kk][wave * 512]);
            gload16(BpS + ko + 128L * ldb, &sB[db][kk][4096 + wave * 512]);
        }
    };

    f32x4 acc[8][4];
#pragma unroll
    for (int i = 0; i < 8; ++i)
#pragma unroll
        for (int j = 0; j < 4; ++j)
#pragma unroll
            for (int p = 0; p < 4; ++p) acc[i][j][p] = 0.f;

    stage_plane(0);
    stage_plane(1);
    stage_plane(2);
    stage_plane(3);
    stage_plane(4);
    stage_plane(5);
    asm volatile("s_waitcnt vmcnt(4)" ::: "memory");
    __builtin_amdgcn_s_barrier();

    for (int t = 0; t < NT; ++t) {
        const int db = t & 1;
        const __bf16* A0 = sA[db][0];
        const __bf16* A1 = sA[db][1];
        const __bf16* B0 = sB[db][0];
        const __bf16* B1 = sB[db][1];
        bf16x8 af[4], bfx[4];
        // ---- phase 0: kk0, m-half 0 ----
#pragma unroll
        for (int j = 0; j < 4; ++j)
            bfx[j] = *(const bf16x8*)(&B0[(brow + j * 16) * 32 + sq8]);
#pragma unroll
        for (int ii = 0; ii < 4; ++ii)
            af[ii] = *(const bf16x8*)(&A0[(arow + ii * 16) * 32 + sq8]);
        stage_plane(4 * t + 6);
        __builtin_amdgcn_s_barrier();
        __builtin_amdgcn_s_setprio(1);
#pragma unroll
        for (int ii = 0; ii < 4; ++ii)
#pragma unroll
            for (int j = 0; j < 4; ++j)
                acc[ii][j] =
                    __builtin_amdgcn_mfma_f32_16x16x32_bf16(af[ii], bfx[j], acc[ii][j], 0, 0, 0);
        __builtin_amdgcn_s_setprio(0);
        __builtin_amdgcn_s_barrier();
        // ---- phase 1: kk0, m-half 1 ----
#pragma unroll
        for (int ii = 0; ii < 4; ++ii)
            af[ii] = *(const bf16x8*)(&A0[(arow + 64 + ii * 16) * 32 + sq8]);
        stage_plane(4 * t + 7);
        __builtin_amdgcn_s_barrier();
        __builtin_amdgcn_s_setprio(1);
#pragma unroll
        for (int ii = 0; ii < 4; ++ii)
#pragma unroll
            for (int j = 0; j < 4; ++j)
                acc[4 + ii][j] = __builtin_amdgcn_mfma_f32_16x16x32_bf16(af[ii], bfx[j],
                                                                         acc[4 + ii][j], 0, 0, 0);
        __builtin_amdgcn_s_setprio(0);
        __builtin_amdgcn_s_barrier();
        // ---- phase 2: kk1, m-half 0 ----
#pragma unroll
        for (int j = 0; j < 4; ++j)
            bfx[j] = *(const bf16x8*)(&B1[(brow + j * 16) * 32 + sq8]);
#pragma unroll
        for (int ii = 0; ii < 4; ++ii)
            af[ii] = *(const bf16x8*)(&A1[(arow + ii * 16) * 32 + sq8]);
        stage_plane(4 * t + 8);
        __builtin_amdgcn_s_barrier();
        __builtin_amdgcn_s_setprio(1);
#pragma unroll
        for (int ii = 0; ii < 4; ++ii)
#pragma unroll
            for (int j = 0; j < 4; ++j)
                acc[ii][j] =
                    __builtin_amdgcn_mfma_f32_16x16x32_bf16(af[ii], bfx[j], acc[ii][j], 0, 0, 0);
        __builtin_amdgcn_s_setprio(0);
        __builtin_amdgcn_s_barrier();
        // ---- phase 3: kk1, m-half 1 ----
#pragma unroll
        for (int ii = 0; ii < 4; ++ii)
            af[ii] = *(const bf16x8*)(&A1[(arow + 64 + ii * 16) * 32 + sq8]);
        stage_plane(4 * t + 9);
        __builtin_amdgcn_s_barrier();
        __builtin_amdgcn_s_setprio(1);
#pragma unroll
        for (int ii = 0; ii < 4; ++ii)
#pragma unroll
            for (int j = 0; j < 4; ++j)
                acc[4 + ii][j] = __builtin_amdgcn_mfma_f32_16x16x32_bf16(af[ii], bfx[j],
                                                                         acc[4 + ii][j], 0, 0, 0);
        __builtin_amdgcn_s_setprio(0);
        asm volatile("s_waitcnt vmcnt(4)" ::: "memory");
        __builtin_amdgcn_s_barrier();
    }
    // epilogue: relu(acc + bias) -> bf16
#pragma unroll
    for (int i = 0; i < 8; ++i) {
#pragma unroll
        for (int p = 0; p < 4; ++p) {
            const int m = m0 + wr * 128 + i * 16 + quad * 4 + p;
#pragma unroll
            for (int j = 0; j < 4; ++j) {
                const int n = n0 + wc * 64 + j * 16 + lane15;
                outB[(long)m * ldout + n] = f2bf(fmaxf(acc[i][j][p] + bias[n], 0.f));
            }
        }
    }
}

// ---------------- flash attention, kc-split x2 -----------------------------------
__global__ __launch_bounds__(256, 4) void k_attn(const bf16* __restrict__ qkv,
                                                 float* __restrict__ po0,
                                                 float* __restrict__ po1,
                                                 float* __restrict__ rs0,
                                                 float* __restrict__ rs1) {
    __shared__ __bf16 sK[64 * 72];
    __shared__ __bf16 sVt[64 * 72];
    const int bh = blockIdx.y;
    const int q0 = blockIdx.x * 128;
    const int z = blockIdx.z;
    const int kc0 = z << 10;
    float* __restrict__ po = z ? po1 : po0;
    float* __restrict__ rsb = z ? rs1 : rs0;
    const int tid = threadIdx.x, wave = tid >> 6, lane = tid & 63;
    const int lane31 = lane & 31, laneh = lane >> 5;
    const bf16* Qp = qkv + (long)bh * 131072;
    const bf16* Kp = qkv + 4194304L + (long)bh * 131072;
    const bf16* Vtp = qkv + 8388608L + (long)bh * 131072;
    bf16x8 qa[4];
#pragma unroll
    for (int s = 0; s < 4; ++s)
        qa[s] = *(const bf16x8*)(&Qp[(long)(q0 + wave * 32 + lane31) * HSq + s * 16 + laneh * 8]);
    f32x16 o[2];
#pragma unroll
    for (int dt = 0; dt < 2; ++dt)
#pragma unroll
        for (int r = 0; r < 16; ++r) o[dt][r] = 0.f;
    float rs = 0.f;
    const int r0 = tid >> 3, c0 = (tid & 7) * 8;
    const int r1 = r0 + 32;

    uint4 nk0 = *(const uint4*)(&Kp[(long)(kc0 + r0) * HSq + c0]);
    uint4 nk1 = *(const uint4*)(&Kp[(long)(kc0 + r1) * HSq + c0]);
    uint4 nv0 = *(const uint4*)(&Vtp[(long)r0 * Tq + kc0 + c0]);
    uint4 nv1 = *(const uint4*)(&Vtp[(long)r1 * Tq + kc0 + c0]);

    for (int kc = kc0; kc < kc0 + 1024; kc += 64) {
        __syncthreads();
        *(uint4*)(&sK[r0 * 72 + c0]) = nk0;
        *(uint4*)(&sK[r1 * 72 + c0]) = nk1;
        *(uint4*)(&sVt[r0 * 72 + c0]) = nv0;
        *(uint4*)(&sVt[r1 * 72 + c0]) = nv1;
        __syncthreads();
        if (kc + 64 < kc0 + 1024) {
            nk0 = *(const uint4*)(&Kp[(long)(kc + 64 + r0) * HSq + c0]);
            nk1 = *(const uint4*)(&Kp[(long)(kc + 64 + r1) * HSq + c0]);
            nv0 = *(const uint4*)(&Vtp[(long)r0 * Tq + kc + 64 + c0]);
            nv1 = *(const uint4*)(&Vtp[(long)r1 * Tq + kc + 64 + c0]);
        }
#pragma unroll
        for (int nt = 0; nt < 2; ++nt) {
            f32x16 zz;
#pragma unroll
            for (int r = 0; r < 16; ++r) zz[r] = 0.f;
            __builtin_amdgcn_s_setprio(1);
#pragma unroll
            for (int s = 0; s < 4; ++s) {
                bf16x8 kb =
                    *(const bf16x8*)(&sK[(nt * 32 + lane31) * 72 + s * 16 + laneh * 8]);
                zz = __builtin_amdgcn_mfma_f32_32x32x16_bf16(kb, qa[s], zz, 0, 0, 0);
            }
            __builtin_amdgcn_s_setprio(0);
            float e[16];
#pragma unroll
            for (int r = 0; r < 16; ++r) {
                e[r] = __expf(zz[r]);
                rs += e[r];
            }
            unsigned int pk[8];
#pragma unroll
            for (int g = 0; g < 4; ++g)
#pragma unroll
                for (int h = 0; h < 2; ++h)
                    pk[g * 2 + h] = (unsigned int)f2u(e[g * 4 + 2 * h]) |
                                    ((unsigned int)f2u(e[g * 4 + 2 * h + 1]) << 16);
            unsigned int sa0 = laneh ? pk[0] : pk[2], sa1 = laneh ? pk[1] : pk[3];
            unsigned int ra0 = __shfl_xor((int)sa0, 32), ra1 = __shfl_xor((int)sa1, 32);
            unsigned int sb0 = laneh ? pk[4] : pk[6], sb1 = laneh ? pk[5] : pk[7];
            unsigned int rb0 = __shfl_xor((int)sb0, 32), rb1 = __shfl_xor((int)sb1, 32);
            uint4 f0, f1;
            if (laneh == 0) {
                f0 = {pk[0], pk[1], ra0, ra1};
                f1 = {pk[4], pk[5], rb0, rb1};
            } else {
                f0 = {ra0, ra1, pk[2], pk[3]};
                f1 = {rb0, rb1, pk[6], pk[7]};
            }
            bf16x8 pa0 = __builtin_bit_cast(bf16x8, f0);
            bf16x8 pa1 = __builtin_bit_cast(bf16x8, f1);
            __builtin_amdgcn_s_setprio(1);
#pragma unroll
            for (int dt = 0; dt < 2; ++dt) {
                bf16x8 vb0 =
                    *(const bf16x8*)(&sVt[(dt * 32 + lane31) * 72 + nt * 32 + laneh * 8]);
                bf16x8 vb1 = *(const bf16x8*)(&sVt[(dt * 32 + lane31) * 72 + nt * 32 + 16 +
                                                   laneh * 8]);
                o[dt] = __builtin_amdgcn_mfma_f32_32x32x16_bf16(pa0, vb0, o[dt], 0, 0, 0);
                o[dt] = __builtin_amdgcn_mfma_f32_32x32x16_bf16(pa1, vb1, o[dt], 0, 0, 0);
            }
            __builtin_amdgcn_s_setprio(0);
        }
    }
    // partial epilogue: store unnormalized O (f32) + this half's row sums
    float ltot = rs + __shfl_xor(rs, 32);
    if (laneh == 0) rsb[(bh << 11) + q0 + wave * 32 + lane31] = ltot;
#pragma unroll
    for (int r = 0; r < 16; ++r) {
        const int tl = (r & 3) + 8 * (r >> 2) + 4 * laneh;
        const int t = q0 + wave * 32 + tl;
        float* pb = po + ((long)(bh << 11) + t) * 64;
#pragma unroll
        for (int dt = 0; dt < 2; ++dt) pb[dt * 32 + lane31] = o[dt][r];
    }
}

// combine: out[b][t][h*64+d] = bf16((po0+po1) / (rs0+rs1)) — 4 floats/thread
__global__ __launch_bounds__(256) void k_attn_combine(
    const float* __restrict__ po0, const float* __restrict__ po1,
    const float* __restrict__ rs0, const float* __restrict__ rs1,
    bf16* __restrict__ out) {
    const long i = ((long)blockIdx.x * 256 + threadIdx.x) * 4;
    const int d = (int)(i & 63);
    const long qq = i >> 6;  // bh*2048 + t
    const int bh = (int)(qq >> 11), t = (int)(qq & 2047);
    const float inv = 1.0f / (rs0[qq] + rs1[qq]);
    const f32x4 a = *(const f32x4*)(po0 + i);
    const f32x4 b = *(const f32x4*)(po1 + i);
    const int bb = bh >> 4, hh = bh & 15;
    ushort4 pk;
    pk.x = f2u((a[0] + b[0]) * inv);
    pk.y = f2u((a[1] + b[1]) * inv);
    pk.z = f2u((a[2] + b[2]) * inv);
    pk.w = f2u((a[3] + b[3]) * inv);
    *(ushort4*)(&out[(((long)bb * Tq + t) << 10) + hh * 64 + d]) = pk;
}

extern "C" void kernel_launch(void* const* d_in, const int* in_sizes, int n_in,
                              void* d_out, int out_size, void* d_ws, size_t ws_size,
                              hipStream_t stream) {
    const float* x = (const float*)d_in[0];
    const float* Wq = (const float*)d_in[1];
    const float* bqv = (const float*)d_in[2];
    const float* Wk = (const float*)d_in[3];
    const float* bkv = (const float*)d_in[4];
    const float* Wv = (const float*)d_in[5];
    const float* bvv = (const float*)d_in[6];
    const float* Wo = (const float*)d_in[7];
    const float* bo = (const float*)d_in[8];
    const float* W1 = (const float*)d_in[9];
    const float* b1 = (const float*)d_in[10];
    const float* W2 = (const float*)d_in[11];
    const float* b2 = (const float*)d_in[12];
    const float* g1 = (const float*)d_in[13];
    const float* be1 = (const float*)d_in[14];
    const float* g2 = (const float*)d_in[15];
    const float* be2 = (const float*)d_in[16];

    // ---- workspace: ~56.7 MiB total (safe under 64 MiB) ----
    char* ws = (char*)d_ws;
    size_t off = 0;
    auto alloc = [&](size_t bytes) {
        void* p = ws + off;
        off += (bytes + 255) & ~(size_t)255;
        return p;
    };
    bf16* regA = (bf16*)alloc(32L * 1024 * 1024);  // qkv (24 MiB)+attn_out tail, then a1 (32 MiB)
    float* x2 = (float*)alloc(4096L * 1024 * 4);   // 16 MiB: attn po0 scratch, then f32 residual
    bf16* buf1 = (bf16*)alloc(4096L * 1024 * 2);   // 8 MiB: WqkvT -> WoT -> W1T -> W2T
    float* bqkv = (float*)alloc(3072L * 4);
    float* ps = (float*)alloc(32L * Bq * Cq * 4);  // LN partials; attn rs0 scratch
    float* pss = (float*)alloc(32L * Bq * Cq * 4); // LN partials; attn rs1 scratch
    float* mean1 = (float*)alloc(Bq * Cq * 4);
    float* rstd1 = (float*)alloc(Bq * Cq * 4);
    float* mean2 = (float*)alloc(Bq * Cq * 4);
    float* rstd2 = (float*)alloc(Bq * Cq * 4);
    bf16* dres = (bf16*)d_out;          // d_out first 8 MiB bf16 scratch: h -> h2
    float* outF = (float*)d_out;
    float* po1 = (float*)d_out;         // full 16 MiB of d_out as attn po1 (h dead then)
    bf16* attn_out = regA + 12582912;   // 8 MiB free tail of regA (qkv uses 24 of 32 MiB)

    // LN1 -> h (bf16, in d_out)
    k_ln_part<<<dim3(4, Bq, 32), 256, 0, stream>>>(x, ps, pss);
    k_ln_fin<<<dim3(8), 256, 0, stream>>>(ps, pss, mean1, rstd1);
    k_ln_apply<<<dim3(16384), 256, 0, stream>>>(x, mean1, rstd1, g1, be1, dres);

    // Wq/Wk/Wv per-head transpose + bias pack (single launch)
    k_transpose3<<<dim3(2, 32, 48), 256, 0, stream>>>(Wq, Wk, Wv, bqv, bkv, bvv, buf1, bqkv);
    // QKV projection -> q(scaled),k,vt in regA
    k_gemm_nt<0><<<dim3(24, 32), 256, 0, stream>>>(dres, 1024, buf1, 1024, 1024, bqkv, regA, 0);
    // attention kc-split x2 -> partials (po0=x2, po1=d_out, rs in ps/pss)
    k_attn<<<dim3(16, 32, 2), 256, 0, stream>>>(regA, x2, po1, ps, pss);
    k_attn_combine<<<dim3(4096), 256, 0, stream>>>(x2, po1, ps, pss, attn_out);
    // Wo^T -> buf1; x2 = attn@Wo + bo + x   (pipelined 128x64, 512 blocks, 2/CU)
    k_transpose<<<dim3(32, 32, 1), 256, 0, stream>>>(Wo, buf1, 1024, 1024, 0, 0);
    k_gemm_n64p<1><<<dim3(16, 32), 256, 0, stream>>>(attn_out, 1024, buf1, 1024, 1024, bo, x,
                                                     x2, 1024);
    // LN2 -> h2 (bf16, in d_out; po1 dead)
    k_ln_part<<<dim3(4, Bq, 32), 256, 0, stream>>>(x2, ps, pss);
    k_ln_fin<<<dim3(8), 256, 0, stream>>>(ps, pss, mean2, rstd2);
    k_ln_apply<<<dim3(16384), 256, 0, stream>>>(x2, mean2, rstd2, g2, be2, dres);

    // ---- FF ----
    k_transpose<<<dim3(128, 32, 1), 256, 0, stream>>>(W1, buf1, 1024, 4096, 0, 0);  // W1T
    // a1 = relu(h2 @ W1T + b1) -> regA [4096][4096] bf16  (8-phase 256^2 pipeline)
    k_gemm_8ph<<<dim3(16, 16), 512, 0, stream>>>(dres, 1024, buf1, 1024, 1024, b1, regA, 4096);
    k_transpose<<<dim3(32, 128, 1), 256, 0, stream>>>(W2, buf1, 4096, 1024, 0, 0);  // W2T
    // d_out(f32) = a1 @ W2T + b2 + x2   (pipelined 128x64, 512 blocks, 2/CU)
    k_gemm_n64p<3><<<dim3(16, 32), 256, 0, stream>>>(regA, 4096, buf1, 4096, 4096, b2, x2,
                                                     outF, 1024);
}